// Round 3
// baseline (814.267 us; speedup 1.0000x reference)
//
#include <hip/hip_runtime.h>
#include <cmath>

#define B_   8
#define N_   1024
#define C_   768
#define H_   12
#define D_   64
#define HID_ 3072
#define M_   8192   // B_*N_

using frag  = __attribute__((ext_vector_type(8))) short;   // 8 bf16
using f32x4 = __attribute__((ext_vector_type(4))) float;
using s4v   = __attribute__((ext_vector_type(4))) short;

__device__ __forceinline__ short f2bf(float x) {
    union { float f; unsigned u; } v; v.f = x;
    unsigned r = (v.u + 0x7FFFu + ((v.u >> 16) & 1u)) >> 16;  // RNE
    return (short)r;
}
__device__ __forceinline__ float gelu_exact(float x) {
    return 0.5f * x * (1.0f + erff(x * 0.70710678118654752f));
}
__device__ __forceinline__ void gload16(const void* g, void* l) {
    __builtin_amdgcn_global_load_lds(
        (const __attribute__((address_space(1))) void*)g,
        (__attribute__((address_space(3))) void*)l, 16, 0, 0);
}

// ---------------- fp32 -> bf16 bulk convert ----------------
__global__ __launch_bounds__(256)
void cvt_bf16(const float* __restrict__ src, short* __restrict__ dst, int n)
{
    int i = (blockIdx.x * 256 + threadIdx.x) * 4;
    if (i < n) {
        float4 u = *(const float4*)(src + i);
        s4v s; s[0] = f2bf(u.x); s[1] = f2bf(u.y); s[2] = f2bf(u.z); s[3] = f2bf(u.w);
        *(s4v*)(dst + i) = s;
    }
}

// ---------------- LayerNorm fp32 -> bf16 ----------------
__global__ __launch_bounds__(256)
void ln_bf16(const float* __restrict__ x, const float* __restrict__ g,
             const float* __restrict__ b, short* __restrict__ y)
{
    __shared__ float red[256];
    const long row = blockIdx.x;
    const float* xr = x + row * C_;
    short* yr = y + row * C_;
    const int t = threadIdx.x;
    float v0 = xr[t], v1 = xr[t + 256], v2 = xr[t + 512];
    red[t] = v0 + v1 + v2;
    __syncthreads();
    for (int o = 128; o > 0; o >>= 1) { if (t < o) red[t] += red[t + o]; __syncthreads(); }
    const float mu = red[0] * (1.0f / 768.0f);
    __syncthreads();
    const float d0 = v0 - mu, d1 = v1 - mu, d2 = v2 - mu;
    red[t] = d0 * d0 + d1 * d1 + d2 * d2;
    __syncthreads();
    for (int o = 128; o > 0; o >>= 1) { if (t < o) red[t] += red[t + o]; __syncthreads(); }
    const float rstd = rsqrtf(red[0] * (1.0f / 768.0f) + 1e-5f);
    yr[t]       = f2bf(d0 * rstd * g[t]       + b[t]);
    yr[t + 256] = f2bf(d1 * rstd * g[t + 256] + b[t + 256]);
    yr[t + 512] = f2bf(d2 * rstd * g[t + 512] + b[t + 512]);
}

// ---------------- MFMA GEMM: C = alpha*A@B^T (+bias)(+res)(gelu) ----------------
// A: [M,K] bf16, B: [N,K] bf16. BK=64. LDS row = 64 bf16 = 8 chunks of 16B,
// chunk l stored at physical slot l ^ (row&7); staged via global_load_lds with
// pre-swizzled global source (linear LDS dest). Optional softmax stats epilogue.
template<int BM, int BN, int WGM, int WGN, bool OUTF32, bool ACT_GELU, bool STATS>
__global__ __launch_bounds__(256)
void gemm_mfma(const short* __restrict__ Ap, int lda, long sAb, long sAh,
               const short* __restrict__ Bp, int ldb, long sBb, long sBh,
               const float* __restrict__ bias,
               const float* __restrict__ res, int ldres,
               void* __restrict__ Cp, int ldc, long sCb, long sCh,
               float2* __restrict__ st,
               int K, float alpha)
{
    constexpr int FM = BM / (WGM * 16), FN = BN / (WGN * 16);
    __shared__ short As[BM * 64];
    __shared__ short Bs[BN * 64];
    const int tid = threadIdx.x;
    const int wid = tid >> 6, lane = tid & 63;
    const int z = blockIdx.z, zb = z / H_, zh = z - zb * H_;
    const long m0 = (long)blockIdx.y * BM;
    const int  n0 = blockIdx.x * BN;
    const short* Ab = Ap + zb * sAb + zh * sAh + m0 * lda;
    const short* Bb = Bp + zb * sBb + zh * sBh + (long)n0 * ldb;
    f32x4 acc[FM][FN] = {};
    const int wr = wid / WGN, wc = wid - wr * WGN;
    const int srow = lane >> 3;                  // row within 8-row group
    const int schunk = (lane & 7) ^ srow;        // pre-swizzled source chunk

    for (int k0 = 0; k0 < K; k0 += 64) {
        for (int g = wid; g < BM / 8; g += 4)
            gload16(Ab + (long)(g * 8 + srow) * lda + k0 + schunk * 8, &As[g * 512]);
        for (int g = wid; g < BN / 8; g += 4)
            gload16(Bb + (long)(g * 8 + srow) * ldb + k0 + schunk * 8, &Bs[g * 512]);
        __syncthreads();
        #pragma unroll
        for (int kk = 0; kk < 2; ++kk) {
            frag a[FM], b[FN];
            #pragma unroll
            for (int fm = 0; fm < FM; ++fm) {
                const int r = wr * FM * 16 + fm * 16 + (lane & 15);
                const int ph = (kk * 4 + (lane >> 4)) ^ (r & 7);
                a[fm] = *(const frag*)&As[r * 64 + ph * 8];
            }
            #pragma unroll
            for (int fn = 0; fn < FN; ++fn) {
                const int r = wc * FN * 16 + fn * 16 + (lane & 15);
                const int ph = (kk * 4 + (lane >> 4)) ^ (r & 7);
                b[fn] = *(const frag*)&Bs[r * 64 + ph * 8];
            }
            #pragma unroll
            for (int fm = 0; fm < FM; ++fm)
                #pragma unroll
                for (int fn = 0; fn < FN; ++fn)
                    acc[fm][fn] = __builtin_amdgcn_mfma_f32_16x16x32_bf16(a[fm], b[fn], acc[fm][fn], 0, 0, 0);
        }
        __syncthreads();
    }

    // ---- C store ----
    float* Cf = (float*)Cp; short* Cs = (short*)Cp;
    const long cbase = zb * sCb + zh * sCh;
    #pragma unroll
    for (int fm = 0; fm < FM; ++fm) {
        #pragma unroll
        for (int fn = 0; fn < FN; ++fn) {
            const long rg = m0 + wr * FM * 16 + fm * 16 + ((lane >> 4) * 4);
            const int  cg = n0 + wc * FN * 16 + fn * 16 + (lane & 15);
            const float bv = bias ? bias[cg] : 0.0f;
            #pragma unroll
            for (int q = 0; q < 4; ++q) {
                const long row = rg + q;
                float v = acc[fm][fn][q] * alpha + bv;
                if (res) v += res[row * (long)ldres + cg];
                if constexpr (ACT_GELU) v = gelu_exact(v);
                if constexpr (OUTF32) Cf[cbase + row * ldc + cg] = v;
                else                  Cs[cbase + row * ldc + cg] = f2bf(v);
            }
        }
    }

    // ---- softmax stats epilogue (per-row tile max + expsum over this BN block) ----
    if constexpr (STATS) {
        float* sred = (float*)As;   // >= 2*BM floats
        float tmax[FM][4];
        #pragma unroll
        for (int fm = 0; fm < FM; ++fm)
            #pragma unroll
            for (int q = 0; q < 4; ++q) {
                float v = acc[fm][0][q];
                #pragma unroll
                for (int fn = 1; fn < FN; ++fn) v = fmaxf(v, acc[fm][fn][q]);
                v *= alpha;   // alpha > 0
                v = fmaxf(v, __shfl_xor(v, 1));
                v = fmaxf(v, __shfl_xor(v, 2));
                v = fmaxf(v, __shfl_xor(v, 4));
                v = fmaxf(v, __shfl_xor(v, 8));
                tmax[fm][q] = v;
                const int r = wr * FM * 16 + fm * 16 + (lane >> 4) * 4 + q;
                if ((lane & 15) == 0) sred[wc * BM + r] = v;
            }
        __syncthreads();
        #pragma unroll
        for (int fm = 0; fm < FM; ++fm)
            #pragma unroll
            for (int q = 0; q < 4; ++q) {
                const int r = wr * FM * 16 + fm * 16 + (lane >> 4) * 4 + q;
                tmax[fm][q] = fmaxf(sred[r], sred[BM + r]);
            }
        __syncthreads();
        #pragma unroll
        for (int fm = 0; fm < FM; ++fm)
            #pragma unroll
            for (int q = 0; q < 4; ++q) {
                float e = 0.0f;
                #pragma unroll
                for (int fn = 0; fn < FN; ++fn)
                    e += __expf(acc[fm][fn][q] * alpha - tmax[fm][q]);
                e += __shfl_xor(e, 1);
                e += __shfl_xor(e, 2);
                e += __shfl_xor(e, 4);
                e += __shfl_xor(e, 8);
                const int r = wr * FM * 16 + fm * 16 + (lane >> 4) * 4 + q;
                if ((lane & 15) == 0) sred[wc * BM + r] = e;
            }
        __syncthreads();
        if (wc == 0) {
            #pragma unroll
            for (int fm = 0; fm < FM; ++fm)
                #pragma unroll
                for (int q = 0; q < 4; ++q) {
                    const int r = wr * FM * 16 + fm * 16 + (lane >> 4) * 4 + q;
                    if ((lane & 15) == 0) {
                        float2 o; o.x = tmax[fm][q]; o.y = sred[r] + sred[BM + r];
                        st[((long)z * N_ + m0 + r) * 8 + blockIdx.x] = o;
                    }
                }
        }
    }
}

// ---------------- fused softmax + head-mix + BN + PV ----------------
// Block = (batch b, 16 query rows), 256 thr / 4 waves. Reads S fp32 once,
// writes final attn fp32 IN PLACE (same thread reads h-planes & writes o-planes
// at identical (n,m) addresses), keeps mixed P bf16 swizzled in LDS, PV via
// MFMA against vT fragments straight from global (L2-resident, 1.5 MB/batch).
__global__ __launch_bounds__(256)
void smpv(float* Sbuf, const float2* __restrict__ st, const short* __restrict__ vT,
          short* __restrict__ Obf,
          const float* __restrict__ cw, const float* __restrict__ cb,
          const float* __restrict__ bg, const float* __restrict__ bb,
          const float* __restrict__ brm, const float* __restrict__ brv)
{
    __shared__ float smx[H_][16], sinv[H_][16];
    __shared__ float coef[H_][H_], baseA[H_], scA[H_];
    __shared__ short pm[H_ * 16 * 64];       // 24 KB, XOR-swizzled rows
    const int t = threadIdx.x;
    const int b = blockIdx.x >> 6, rblk = blockIdx.x & 63;
    const int n0 = rblk * 16;

    if (t < H_) {
        const float s = bg[t] * rsqrtf(brv[t] + 1e-5f);
        scA[t] = s;
        baseA[t] = (cb[t] - brm[t]) * s + bb[t];
    }
    __syncthreads();
    if (t < H_ * H_) coef[t / H_][t % H_] = cw[t] * scA[t / H_];
    if (t < 192) {
        const int h = t >> 4, r = t & 15;
        const float2* sp = st + ((long)(b * H_ + h) * N_ + n0 + r) * 8;
        float2 sv[8];
        #pragma unroll
        for (int i = 0; i < 8; ++i) sv[i] = sp[i];
        float gm = sv[0].x;
        #pragma unroll
        for (int i = 1; i < 8; ++i) gm = fmaxf(gm, sv[i].x);
        float gs = 0.0f;
        #pragma unroll
        for (int i = 0; i < 8; ++i) gs += sv[i].y * __expf(sv[i].x - gm);
        smx[h][r] = gm;
        sinv[h][r] = 1.0f / gs;
    }
    __syncthreads();

    const int r = t >> 4, m4 = t & 15;
    const int wv = t >> 6, lane = t & 63;
    f32x4 acc[3][4] = {};

    for (int mc = 0; mc < 16; ++mc) {
        const int m0 = mc * 64;
        float4 p[H_];
        #pragma unroll
        for (int h = 0; h < H_; ++h) {
            const float4 sv = *(const float4*)&Sbuf[((long)(b * H_ + h) << 20) +
                                                    ((long)(n0 + r) << 10) + m0 + m4 * 4];
            const float gm = smx[h][r], gi = sinv[h][r];
            float4 e;
            e.x = __expf(sv.x - gm) * gi; e.y = __expf(sv.y - gm) * gi;
            e.z = __expf(sv.z - gm) * gi; e.w = __expf(sv.w - gm) * gi;
            p[h] = e;
        }
        #pragma unroll
        for (int o = 0; o < H_; ++o) {
            const float bse = baseA[o];
            float4 a; a.x = bse; a.y = bse; a.z = bse; a.w = bse;
            #pragma unroll
            for (int h = 0; h < H_; ++h) {
                const float w = coef[o][h];
                a.x += w * p[h].x; a.y += w * p[h].y;
                a.z += w * p[h].z; a.w += w * p[h].w;
            }
            *(float4*)&Sbuf[((long)(b * H_ + o) << 20) + ((long)(n0 + r) << 10) + m0 + m4 * 4] = a;
            s4v pb; pb[0] = f2bf(a.x); pb[1] = f2bf(a.y); pb[2] = f2bf(a.z); pb[3] = f2bf(a.w);
            const int ph = (m4 >> 1) ^ (r & 7);
            *(s4v*)&pm[(o * 16 + r) * 64 + ph * 8 + (m4 & 1) * 4] = pb;
        }
        __syncthreads();
        #pragma unroll
        for (int j = 0; j < 3; ++j) {
            const int o = wv * 3 + j;
            #pragma unroll
            for (int kk = 0; kk < 2; ++kk) {
                const int ra = lane & 15;
                const int ph = (kk * 4 + (lane >> 4)) ^ (ra & 7);
                const frag a = *(const frag*)&pm[(o * 16 + ra) * 64 + ph * 8];
                #pragma unroll
                for (int f = 0; f < 4; ++f) {
                    const int d = f * 16 + (lane & 15);
                    const frag bv = *(const frag*)&vT[((long)(b * H_ + o) * D_ + d) * N_ +
                                                      m0 + kk * 32 + (lane >> 4) * 8];
                    acc[j][f] = __builtin_amdgcn_mfma_f32_16x16x32_bf16(a, bv, acc[j][f], 0, 0, 0);
                }
            }
        }
        __syncthreads();
    }
    #pragma unroll
    for (int j = 0; j < 3; ++j) {
        const int o = wv * 3 + j;
        #pragma unroll
        for (int f = 0; f < 4; ++f) {
            #pragma unroll
            for (int q = 0; q < 4; ++q) {
                const int row = (lane >> 4) * 4 + q;
                const int col = o * D_ + f * 16 + (lane & 15);
                Obf[((long)(b * N_ + n0 + row)) * C_ + col] = f2bf(acc[j][f][q]);
            }
        }
    }
}

// ---------------- v transpose: qkv bf16 [B*N,2304] -> vT [B*H][64][1024] ----------------
__global__ __launch_bounds__(256)
void vtrans(const short* __restrict__ qkv, short* __restrict__ vT)
{
    __shared__ short tile[64][72];
    const int bh = blockIdx.x;
    const int n0 = blockIdx.y * 64;
    const int b = bh / H_, h = bh - b * H_;
    const short* src = qkv + (long)b * N_ * (3 * C_) + 2 * C_ + h * D_;
    const int t = threadIdx.x;
    {
        const int r = t >> 2, c = (t & 3) * 16;
        const short* sp = src + (long)(n0 + r) * (3 * C_) + c;
        #pragma unroll
        for (int j = 0; j < 16; j++) tile[r][c + j] = sp[j];
    }
    __syncthreads();
    {
        const int d = t >> 2, c = (t & 3) * 16;
        short* dp = vT + (long)bh * (D_ * N_) + (long)d * N_ + n0 + c;
        #pragma unroll
        for (int j = 0; j < 16; j++) dp[j] = tile[c + j][d];
    }
}

// ---------------- launch ----------------
extern "C" void kernel_launch(void* const* d_in, const int* in_sizes, int n_in,
                              void* d_out, int out_size, void* d_ws, size_t ws_size,
                              hipStream_t stream)
{
    const float* inp    = (const float*)d_in[0];
    const float* ln1_g  = (const float*)d_in[1];
    const float* ln1_b  = (const float*)d_in[2];
    const float* qkv_w  = (const float*)d_in[3];
    const float* conv_w = (const float*)d_in[4];
    const float* conv_b = (const float*)d_in[5];
    const float* bn_g   = (const float*)d_in[6];
    const float* bn_b   = (const float*)d_in[7];
    const float* bn_rm  = (const float*)d_in[8];
    const float* bn_rv  = (const float*)d_in[9];
    const float* proj_w = (const float*)d_in[10];
    const float* proj_b = (const float*)d_in[11];
    const float* ln2_g  = (const float*)d_in[12];
    const float* ln2_b  = (const float*)d_in[13];
    const float* fc1_w  = (const float*)d_in[14];
    const float* fc1_b  = (const float*)d_in[15];
    const float* fc2_w  = (const float*)d_in[16];
    const float* fc2_b  = (const float*)d_in[17];

    float* outx = (float*)d_out;
    float* attn = outx + (long)M_ * C_;

    char* w = (char*)d_ws;
    short* wqkv  = (short*)w;  w += (long)3 * C_ * C_ * 2;
    short* wproj = (short*)w;  w += (long)C_ * C_ * 2;
    short* wfc1  = (short*)w;  w += (long)HID_ * C_ * 2;
    short* wfc2  = (short*)w;  w += (long)C_ * HID_ * 2;
    short* xln   = (short*)w;  w += (long)M_ * C_ * 2;
    short* qkvb  = (short*)w;
    short* hbuf  = qkvb;       w += (long)M_ * HID_ * 2;   // max(qkv, h) region
    short* vT    = (short*)w;  w += (long)B_ * H_ * D_ * N_ * 2;
    short* Obf   = (short*)w;  w += (long)M_ * C_ * 2;
    float* xres  = (float*)w;  w += (long)M_ * C_ * 4;
    float2* st   = (float2*)w; w += (long)B_ * H_ * N_ * 8 * 8;

    // weights -> bf16
    cvt_bf16<<<(3 * C_ * C_) / 1024, 256, 0, stream>>>(qkv_w, wqkv, 3 * C_ * C_);
    cvt_bf16<<<(C_ * C_) / 1024,     256, 0, stream>>>(proj_w, wproj, C_ * C_);
    cvt_bf16<<<(HID_ * C_) / 1024,   256, 0, stream>>>(fc1_w, wfc1, HID_ * C_);
    cvt_bf16<<<(C_ * HID_) / 1024,   256, 0, stream>>>(fc2_w, wfc2, C_ * HID_);

    // 1) LN1 -> xln (bf16)
    ln_bf16<<<M_, 256, 0, stream>>>(inp, ln1_g, ln1_b, xln);

    // 2) qkv = xln @ qkv_w^T -> bf16 [8192,2304]
    gemm_mfma<128, 128, 2, 2, false, false, false><<<dim3(18, 64, 1), 256, 0, stream>>>(
        xln, C_, 0, 0, wqkv, C_, 0, 0, nullptr, nullptr, 0,
        qkvb, 3 * C_, 0, 0, nullptr, C_, 1.0f);

    // 3) vT = transpose(v)
    vtrans<<<dim3(B_ * H_, 16), 256, 0, stream>>>(qkvb, vT);

    // 4) S = 0.125 * q @ k^T -> fp32 attn + per-tile softmax stats
    gemm_mfma<128, 128, 2, 2, true, false, true><<<dim3(8, 8, 96), 256, 0, stream>>>(
        qkvb,      3 * C_, (long)N_ * 3 * C_, D_,
        qkvb + C_, 3 * C_, (long)N_ * 3 * C_, D_,
        nullptr, nullptr, 0,
        attn, N_, (long)H_ * N_ * N_, (long)N_ * N_, st, D_, 0.125f);

    // 5) fused softmax + mix + BN (in place -> final attn_next) + PV -> Obf
    smpv<<<B_ * 64, 256, 0, stream>>>(attn, st, vT, Obf,
                                      conv_w, conv_b, bn_g, bn_b, bn_rm, bn_rv);

    // 6) x = inputs + O @ proj_w^T + proj_b -> fp32
    gemm_mfma<128, 128, 2, 2, true, false, false><<<dim3(6, 64, 1), 256, 0, stream>>>(
        Obf, C_, 0, 0, wproj, C_, 0, 0, proj_b, inp, C_,
        xres, C_, 0, 0, nullptr, C_, 1.0f);

    // 7) LN2 -> xln (bf16, reuse)
    ln_bf16<<<M_, 256, 0, stream>>>(xres, ln2_g, ln2_b, xln);

    // 8) h = gelu(xln @ fc1_w^T + fc1_b) -> bf16
    gemm_mfma<128, 128, 2, 2, false, true, false><<<dim3(24, 64, 1), 256, 0, stream>>>(
        xln, C_, 0, 0, wfc1, C_, 0, 0, fc1_b, nullptr, 0,
        hbuf, HID_, 0, 0, nullptr, C_, 1.0f);

    // 9) out = x + h @ fc2_w^T + fc2_b -> fp32
    gemm_mfma<128, 128, 2, 2, true, false, false><<<dim3(6, 64, 1), 256, 0, stream>>>(
        hbuf, HID_, 0, 0, wfc2, HID_, 0, 0, fc2_b, xres, C_,
        outx, C_, 0, 0, nullptr, HID_, 1.0f);
}

// Round 4
// 649.326 us; speedup vs baseline: 1.2540x; 1.2540x over previous
//
#include <hip/hip_runtime.h>
#include <cmath>

#define B_   8
#define N_   1024
#define C_   768
#define H_   12
#define D_   64
#define HID_ 3072
#define M_   8192   // B_*N_

using frag  = __attribute__((ext_vector_type(8))) short;   // 8 bf16
using f32x4 = __attribute__((ext_vector_type(4))) float;
using s4v   = __attribute__((ext_vector_type(4))) short;

__device__ __forceinline__ short f2bf(float x) {
    union { float f; unsigned u; } v; v.f = x;
    unsigned r = (v.u + 0x7FFFu + ((v.u >> 16) & 1u)) >> 16;  // RNE
    return (short)r;
}
__device__ __forceinline__ float b2f(short s) {
    union { float f; unsigned u; } v; v.u = ((unsigned)(unsigned short)s) << 16;
    return v.f;
}
__device__ __forceinline__ float bfr(float x) { return b2f(f2bf(x)); }  // round to bf16
__device__ __forceinline__ float gelu_exact(float x) {
    return 0.5f * x * (1.0f + erff(x * 0.70710678118654752f));
}
__device__ __forceinline__ void gload16(const void* g, void* l) {
    __builtin_amdgcn_global_load_lds(
        (const __attribute__((address_space(1))) void*)g,
        (__attribute__((address_space(3))) void*)l, 16, 0, 0);
}

// ---------------- fp32 -> bf16 bulk convert ----------------
__global__ __launch_bounds__(256)
void cvt_bf16(const float* __restrict__ src, short* __restrict__ dst, int n)
{
    int i = (blockIdx.x * 256 + threadIdx.x) * 4;
    if (i < n) {
        float4 u = *(const float4*)(src + i);
        s4v s; s[0] = f2bf(u.x); s[1] = f2bf(u.y); s[2] = f2bf(u.z); s[3] = f2bf(u.w);
        *(s4v*)(dst + i) = s;
    }
}

// ---------------- LayerNorm fp32 -> bf16 ----------------
__global__ __launch_bounds__(256)
void ln_bf16(const float* __restrict__ x, const float* __restrict__ g,
             const float* __restrict__ b, short* __restrict__ y)
{
    __shared__ float red[256];
    const long row = blockIdx.x;
    const float* xr = x + row * C_;
    short* yr = y + row * C_;
    const int t = threadIdx.x;
    float v0 = xr[t], v1 = xr[t + 256], v2 = xr[t + 512];
    red[t] = v0 + v1 + v2;
    __syncthreads();
    for (int o = 128; o > 0; o >>= 1) { if (t < o) red[t] += red[t + o]; __syncthreads(); }
    const float mu = red[0] * (1.0f / 768.0f);
    __syncthreads();
    const float d0 = v0 - mu, d1 = v1 - mu, d2 = v2 - mu;
    red[t] = d0 * d0 + d1 * d1 + d2 * d2;
    __syncthreads();
    for (int o = 128; o > 0; o >>= 1) { if (t < o) red[t] += red[t + o]; __syncthreads(); }
    const float rstd = rsqrtf(red[0] * (1.0f / 768.0f) + 1e-5f);
    yr[t]       = f2bf(d0 * rstd * g[t]       + b[t]);
    yr[t + 256] = f2bf(d1 * rstd * g[t + 256] + b[t + 256]);
    yr[t + 512] = f2bf(d2 * rstd * g[t + 512] + b[t + 512]);
}

// ---------------- MFMA GEMM: C = alpha*A@B^T (+bias)(+res)(gelu)(stats) ----------
// A: [M,K] bf16 (or fp32 reg-staged if AF32). B: [N,K] bf16. BK=64.
// LDS row = 64 bf16 = 8 chunks of 16B; chunk l at physical slot l ^ (row&7).
// bf16 path staged via global_load_lds with pre-swizzled global source.
template<int BM, int BN, int WGM, int WGN, bool AF32, bool OUTF32, bool ACT_GELU, bool STATS>
__global__ __launch_bounds__(256)
void gemm_mfma(const void* __restrict__ Ap, int lda, long sAb, long sAh,
               const short* __restrict__ Bp, int ldb, long sBb, long sBh,
               const float* __restrict__ bias,
               const float* __restrict__ res, int ldres,
               void* __restrict__ Cp, int ldc, long sCb, long sCh,
               float2* __restrict__ st,
               int K, float alpha)
{
    constexpr int FM = BM / (WGM * 16), FN = BN / (WGN * 16);
    __shared__ short As[BM * 64];
    __shared__ short Bs[BN * 64];
    const int tid = threadIdx.x;
    const int wid = tid >> 6, lane = tid & 63;
    const int z = blockIdx.z, zb = z / H_, zh = z - zb * H_;
    const long m0 = (long)blockIdx.y * BM;
    const int  n0 = blockIdx.x * BN;
    const short* Bb = Bp + zb * sBb + zh * sBh + (long)n0 * ldb;
    const short* Abh = nullptr; const float* Afh = nullptr;
    if constexpr (AF32) Afh = (const float*)Ap + zb * sAb + zh * sAh + m0 * lda;
    else                Abh = (const short*)Ap + zb * sAb + zh * sAh + m0 * lda;
    f32x4 acc[FM][FN] = {};
    const int wr = wid / WGN, wc = wid - wr * WGN;
    const int srow = lane >> 3;                  // row within 8-row group
    const int schunk = (lane & 7) ^ srow;        // pre-swizzled source chunk

    for (int k0 = 0; k0 < K; k0 += 64) {
        if constexpr (!AF32) {
            for (int g = wid; g < BM / 8; g += 4)
                gload16(Abh + (long)(g * 8 + srow) * lda + k0 + schunk * 8, &As[g * 512]);
        } else {
            // reg-stage 128x64 fp32 -> bf16 swizzled LDS (BM must be 128)
            const int r = tid >> 1, h2 = tid & 1;
            const float* sp = Afh + (long)r * lda + k0 + h2 * 32;
            #pragma unroll
            for (int j = 0; j < 4; ++j) {
                float4 u0 = *(const float4*)(sp + j * 8);
                float4 u1 = *(const float4*)(sp + j * 8 + 4);
                frag w;
                w[0] = f2bf(u0.x); w[1] = f2bf(u0.y); w[2] = f2bf(u0.z); w[3] = f2bf(u0.w);
                w[4] = f2bf(u1.x); w[5] = f2bf(u1.y); w[6] = f2bf(u1.z); w[7] = f2bf(u1.w);
                *(frag*)&As[r * 64 + (((h2 * 4 + j)) ^ (r & 7)) * 8] = w;
            }
        }
        for (int g = wid; g < BN / 8; g += 4)
            gload16(Bb + (long)(g * 8 + srow) * ldb + k0 + schunk * 8, &Bs[g * 512]);
        __syncthreads();
        #pragma unroll
        for (int kk = 0; kk < 2; ++kk) {
            frag a[FM], b[FN];
            #pragma unroll
            for (int fm = 0; fm < FM; ++fm) {
                const int r = wr * FM * 16 + fm * 16 + (lane & 15);
                const int ph = (kk * 4 + (lane >> 4)) ^ (r & 7);
                a[fm] = *(const frag*)&As[r * 64 + ph * 8];
            }
            #pragma unroll
            for (int fn = 0; fn < FN; ++fn) {
                const int r = wc * FN * 16 + fn * 16 + (lane & 15);
                const int ph = (kk * 4 + (lane >> 4)) ^ (r & 7);
                b[fn] = *(const frag*)&Bs[r * 64 + ph * 8];
            }
            #pragma unroll
            for (int fm = 0; fm < FM; ++fm)
                #pragma unroll
                for (int fn = 0; fn < FN; ++fn)
                    acc[fm][fn] = __builtin_amdgcn_mfma_f32_16x16x32_bf16(a[fm], b[fn], acc[fm][fn], 0, 0, 0);
        }
        __syncthreads();
    }

    // ---- C store ----
    float* Cf = (float*)Cp; short* Cs = (short*)Cp;
    const long cbase = zb * sCb + zh * sCh;
    #pragma unroll
    for (int fm = 0; fm < FM; ++fm) {
        #pragma unroll
        for (int fn = 0; fn < FN; ++fn) {
            const long rg = m0 + wr * FM * 16 + fm * 16 + ((lane >> 4) * 4);
            const int  cg = n0 + wc * FN * 16 + fn * 16 + (lane & 15);
            const float bv = bias ? bias[cg] : 0.0f;
            #pragma unroll
            for (int q = 0; q < 4; ++q) {
                const long row = rg + q;
                float v = acc[fm][fn][q] * alpha + bv;
                if (res) v += res[row * (long)ldres + cg];
                if constexpr (ACT_GELU) v = gelu_exact(v);
                if constexpr (OUTF32) Cf[cbase + row * ldc + cg] = v;
                else                  Cs[cbase + row * ldc + cg] = f2bf(v);
            }
        }
    }

    // ---- softmax stats epilogue: per-row (tile-max, tile-expsum) of bf16-rounded S ----
    if constexpr (STATS) {
        float* sred = (float*)As;   // >= 2*BM floats
        float tmax[FM][4];
        #pragma unroll
        for (int fm = 0; fm < FM; ++fm)
            #pragma unroll
            for (int q = 0; q < 4; ++q) {
                float v = bfr(acc[fm][0][q] * alpha);
                #pragma unroll
                for (int fn = 1; fn < FN; ++fn) v = fmaxf(v, bfr(acc[fm][fn][q] * alpha));
                v = fmaxf(v, __shfl_xor(v, 1));
                v = fmaxf(v, __shfl_xor(v, 2));
                v = fmaxf(v, __shfl_xor(v, 4));
                v = fmaxf(v, __shfl_xor(v, 8));
                const int r = wr * FM * 16 + fm * 16 + (lane >> 4) * 4 + q;
                if ((lane & 15) == 0) sred[wc * BM + r] = v;
            }
        __syncthreads();
        #pragma unroll
        for (int fm = 0; fm < FM; ++fm)
            #pragma unroll
            for (int q = 0; q < 4; ++q) {
                const int r = wr * FM * 16 + fm * 16 + (lane >> 4) * 4 + q;
                tmax[fm][q] = fmaxf(sred[r], sred[BM + r]);
            }
        __syncthreads();
        #pragma unroll
        for (int fm = 0; fm < FM; ++fm)
            #pragma unroll
            for (int q = 0; q < 4; ++q) {
                float e = 0.0f;
                #pragma unroll
                for (int fn = 0; fn < FN; ++fn)
                    e += __expf(bfr(acc[fm][fn][q] * alpha) - tmax[fm][q]);
                e += __shfl_xor(e, 1);
                e += __shfl_xor(e, 2);
                e += __shfl_xor(e, 4);
                e += __shfl_xor(e, 8);
                const int r = wr * FM * 16 + fm * 16 + (lane >> 4) * 4 + q;
                if ((lane & 15) == 0) sred[wc * BM + r] = e;
            }
        __syncthreads();
        if (wc == 0) {
            #pragma unroll
            for (int fm = 0; fm < FM; ++fm)
                #pragma unroll
                for (int q = 0; q < 4; ++q) {
                    const int r = wr * FM * 16 + fm * 16 + (lane >> 4) * 4 + q;
                    if ((lane & 15) == 0) {
                        float2 o; o.x = tmax[fm][q]; o.y = sred[r] + sred[BM + r];
                        st[((long)z * N_ + m0 + r) * 8 + blockIdx.x] = o;
                    }
                }
        }
    }
}

// ---------------- softmax(from stats) + head-mix + BN : bf16 S -> fp32 attn ----------
// One block per (b,n); thread t owns m = t*4..t*4+3 across all 12 heads.
// No block reductions: global row max/sum come from the QKT stats.
__global__ __launch_bounds__(256)
void smb2(const short* __restrict__ S, const float2* __restrict__ st,
          float* __restrict__ attn,
          const float* __restrict__ cw, const float* __restrict__ cb,
          const float* __restrict__ bg, const float* __restrict__ bb,
          const float* __restrict__ brm, const float* __restrict__ brv)
{
    __shared__ float coef[H_][H_], baseA[H_], scA[H_], smx[H_], sinv[H_];
    const int t = threadIdx.x;
    const int bn = blockIdx.x;
    const int b = bn >> 10, n = bn & 1023;
    if (t < H_) {
        const float s = bg[t] * rsqrtf(brv[t] + 1e-5f);
        scA[t] = s;
        baseA[t] = (cb[t] - brm[t]) * s + bb[t];
    }
    __syncthreads();
    if (t < H_ * H_) coef[t / H_][t % H_] = cw[t] * scA[t / H_];
    if (t < H_) {
        const float2* sp = st + ((long)(b * H_ + t) * N_ + n) * 8;
        float2 sv[8];
        #pragma unroll
        for (int i = 0; i < 8; ++i) sv[i] = sp[i];
        float gm = sv[0].x;
        #pragma unroll
        for (int i = 1; i < 8; ++i) gm = fmaxf(gm, sv[i].x);
        float gs = 0.0f;
        #pragma unroll
        for (int i = 0; i < 8; ++i) gs += sv[i].y * __expf(sv[i].x - gm);
        smx[t] = gm;
        sinv[t] = 1.0f / gs;
    }
    __syncthreads();

    const long pstr = (long)N_ * N_;
    const short* sb = S    + (long)b * H_ * pstr + (long)n * N_ + t * 4;
    float*       ab = attn + (long)b * H_ * pstr + (long)n * N_ + t * 4;
    float4 p[H_];
    #pragma unroll
    for (int h = 0; h < H_; ++h) {
        const s4v sv = *(const s4v*)(sb + (long)h * pstr);
        const float gm = smx[h], gi = sinv[h];
        float4 e;
        e.x = __expf(b2f(sv[0]) - gm) * gi;
        e.y = __expf(b2f(sv[1]) - gm) * gi;
        e.z = __expf(b2f(sv[2]) - gm) * gi;
        e.w = __expf(b2f(sv[3]) - gm) * gi;
        p[h] = e;
    }
    #pragma unroll
    for (int o = 0; o < H_; ++o) {
        const float bse = baseA[o];
        float4 a; a.x = bse; a.y = bse; a.z = bse; a.w = bse;
        #pragma unroll
        for (int h = 0; h < H_; ++h) {
            const float w = coef[o][h];
            a.x += w * p[h].x; a.y += w * p[h].y;
            a.z += w * p[h].z; a.w += w * p[h].w;
        }
        *(float4*)(ab + (long)o * pstr) = a;
    }
}

// ---------------- v transpose: qkv bf16 [B*N,2304] -> vT [B*H][64][1024] ----------------
__global__ __launch_bounds__(256)
void vtrans(const short* __restrict__ qkv, short* __restrict__ vT)
{
    __shared__ short tile[64][72];
    const int bh = blockIdx.x;
    const int n0 = blockIdx.y * 64;
    const int b = bh / H_, h = bh - b * H_;
    const short* src = qkv + (long)b * N_ * (3 * C_) + 2 * C_ + h * D_;
    const int t = threadIdx.x;
    {
        const int r = t >> 2, c = (t & 3) * 16;
        const short* sp = src + (long)(n0 + r) * (3 * C_) + c;
        #pragma unroll
        for (int j = 0; j < 16; j++) tile[r][c + j] = sp[j];
    }
    __syncthreads();
    {
        const int d = t >> 2, c = (t & 3) * 16;
        short* dp = vT + (long)bh * (D_ * N_) + (long)d * N_ + n0 + c;
        #pragma unroll
        for (int j = 0; j < 16; j++) dp[j] = tile[c + j][d];
    }
}

// ---------------- launch ----------------
extern "C" void kernel_launch(void* const* d_in, const int* in_sizes, int n_in,
                              void* d_out, int out_size, void* d_ws, size_t ws_size,
                              hipStream_t stream)
{
    const float* inp    = (const float*)d_in[0];
    const float* ln1_g  = (const float*)d_in[1];
    const float* ln1_b  = (const float*)d_in[2];
    const float* qkv_w  = (const float*)d_in[3];
    const float* conv_w = (const float*)d_in[4];
    const float* conv_b = (const float*)d_in[5];
    const float* bn_g   = (const float*)d_in[6];
    const float* bn_b   = (const float*)d_in[7];
    const float* bn_rm  = (const float*)d_in[8];
    const float* bn_rv  = (const float*)d_in[9];
    const float* proj_w = (const float*)d_in[10];
    const float* proj_b = (const float*)d_in[11];
    const float* ln2_g  = (const float*)d_in[12];
    const float* ln2_b  = (const float*)d_in[13];
    const float* fc1_w  = (const float*)d_in[14];
    const float* fc1_b  = (const float*)d_in[15];
    const float* fc2_w  = (const float*)d_in[16];
    const float* fc2_b  = (const float*)d_in[17];

    float* outx = (float*)d_out;
    float* attn = outx + (long)M_ * C_;

    char* w = (char*)d_ws;
    short* wqkv  = (short*)w;  w += (long)3 * C_ * C_ * 2;
    short* wproj = (short*)w;  w += (long)C_ * C_ * 2;
    short* wfc1  = (short*)w;  w += (long)HID_ * C_ * 2;
    short* wfc2  = (short*)w;  w += (long)C_ * HID_ * 2;
    short* xln   = (short*)w;  w += (long)M_ * C_ * 2;
    short* qkvb  = (short*)w;
    short* hbuf  = qkvb;       w += (long)M_ * HID_ * 2;   // max(qkv, h) region
    short* vT    = (short*)w;  w += (long)B_ * H_ * D_ * N_ * 2;
    short* Obf   = (short*)w;  w += (long)M_ * C_ * 2;
    float* xres  = (float*)w;  w += (long)M_ * C_ * 4;
    float2* st   = (float2*)w; w += (long)B_ * H_ * N_ * 8 * 8;
    short* Sbf   = (short*)w;  w += (long)B_ * H_ * N_ * N_ * 2;   // 201 MB

    // weights -> bf16
    cvt_bf16<<<(3 * C_ * C_) / 1024, 256, 0, stream>>>(qkv_w, wqkv, 3 * C_ * C_);
    cvt_bf16<<<(C_ * C_) / 1024,     256, 0, stream>>>(proj_w, wproj, C_ * C_);
    cvt_bf16<<<(HID_ * C_) / 1024,   256, 0, stream>>>(fc1_w, wfc1, HID_ * C_);
    cvt_bf16<<<(C_ * HID_) / 1024,   256, 0, stream>>>(fc2_w, wfc2, C_ * HID_);

    // 1) LN1 -> xln (bf16)
    ln_bf16<<<M_, 256, 0, stream>>>(inp, ln1_g, ln1_b, xln);

    // 2) qkv = xln @ qkv_w^T -> bf16 [8192,2304]
    gemm_mfma<128, 128, 2, 2, false, false, false, false><<<dim3(18, 64, 1), 256, 0, stream>>>(
        xln, C_, 0, 0, wqkv, C_, 0, 0, nullptr, nullptr, 0,
        qkvb, 3 * C_, 0, 0, nullptr, C_, 1.0f);

    // 3) vT = transpose(v)
    vtrans<<<dim3(B_ * H_, 16), 256, 0, stream>>>(qkvb, vT);

    // 4) S = 0.125 * q @ k^T -> bf16 Sbf + per-tile softmax stats
    gemm_mfma<128, 128, 2, 2, false, false, false, true><<<dim3(8, 8, 96), 256, 0, stream>>>(
        qkvb,      3 * C_, (long)N_ * 3 * C_, D_,
        qkvb + C_, 3 * C_, (long)N_ * 3 * C_, D_,
        nullptr, nullptr, 0,
        Sbf, N_, (long)H_ * N_ * N_, (long)N_ * N_, st, D_, 0.125f);

    // 5) softmax(stats) + mix + BN : Sbf -> fp32 attn (final attn_next)
    smb2<<<M_, 256, 0, stream>>>(Sbf, st, attn, conv_w, conv_b, bn_g, bn_b, bn_rm, bn_rv);

    // 6) O = attn @ v -> bf16 [B,N,C] layout (AF32 A path)
    gemm_mfma<128, 64, 4, 1, true, false, false, false><<<dim3(1, 8, 96), 256, 0, stream>>>(
        attn, N_, (long)H_ * N_ * N_, (long)N_ * N_,
        vT, N_, (long)H_ * D_ * N_, (long)D_ * N_,
        nullptr, nullptr, 0,
        Obf, C_, (long)N_ * C_, D_, nullptr, N_, 1.0f);

    // 7) x = inputs + O @ proj_w^T + proj_b -> fp32
    gemm_mfma<128, 128, 2, 2, false, true, false, false><<<dim3(6, 64, 1), 256, 0, stream>>>(
        Obf, C_, 0, 0, wproj, C_, 0, 0, proj_b, inp, C_,
        xres, C_, 0, 0, nullptr, C_, 1.0f);

    // 8) LN2 -> xln (bf16, reuse)
    ln_bf16<<<M_, 256, 0, stream>>>(xres, ln2_g, ln2_b, xln);

    // 9) h = gelu(xln @ fc1_w^T + fc1_b) -> bf16
    gemm_mfma<128, 128, 2, 2, false, false, true, false><<<dim3(24, 64, 1), 256, 0, stream>>>(
        xln, C_, 0, 0, wfc1, C_, 0, 0, fc1_b, nullptr, 0,
        hbuf, HID_, 0, 0, nullptr, C_, 1.0f);

    // 10) out = x + h @ fc2_w^T + fc2_b -> fp32
    gemm_mfma<128, 128, 2, 2, false, true, false, false><<<dim3(6, 64, 1), 256, 0, stream>>>(
        hbuf, HID_, 0, 0, wfc2, HID_, 0, 0, fc2_b, xres, C_,
        outx, C_, 0, 0, nullptr, HID_, 1.0f);
}

// Round 5
// 611.583 us; speedup vs baseline: 1.3314x; 1.0617x over previous
//
#include <hip/hip_runtime.h>
#include <cmath>

#define B_   8
#define N_   1024
#define C_   768
#define H_   12
#define D_   64
#define HID_ 3072
#define M_   8192   // B_*N_

using frag  = __attribute__((ext_vector_type(8))) short;   // 8 bf16
using f32x4 = __attribute__((ext_vector_type(4))) float;
using s4v   = __attribute__((ext_vector_type(4))) short;

__device__ __forceinline__ short f2bf(float x) {
    union { float f; unsigned u; } v; v.f = x;
    unsigned r = (v.u + 0x7FFFu + ((v.u >> 16) & 1u)) >> 16;  // RNE
    return (short)r;
}
__device__ __forceinline__ float b2f(short s) {
    union { float f; unsigned u; } v; v.u = ((unsigned)(unsigned short)s) << 16;
    return v.f;
}
__device__ __forceinline__ float bfr(float x) { return b2f(f2bf(x)); }  // round to bf16
__device__ __forceinline__ float gelu_exact(float x) {
    return 0.5f * x * (1.0f + erff(x * 0.70710678118654752f));
}
__device__ __forceinline__ void gload16(const void* g, void* l) {
    __builtin_amdgcn_global_load_lds(
        (const __attribute__((address_space(1))) void*)g,
        (__attribute__((address_space(3))) void*)l, 16, 0, 0);
}

// Bijective XCD-aware tile swizzle (m204): hardware round-robins linear block id
// across 8 XCDs; remap so each XCD owns a contiguous chunk of logical tiles
// (all column-tiles of an A-row-band land on one XCD -> band fetched once).
__device__ __forceinline__ int2 swz_xy() {
    const int gx = gridDim.x;
    const int nwg = gx * gridDim.y;
    const int orig = blockIdx.y * gx + blockIdx.x;
    const int q = nwg >> 3, r = nwg & 7;
    const int xcd = orig & 7;
    const int base = (xcd < r) ? xcd * (q + 1) : r * (q + 1) + (xcd - r) * q;
    const int wgid = base + (orig >> 3);
    int2 v; v.x = wgid % gx; v.y = wgid / gx;
    return v;
}

// ---------------- fused weights fp32 -> bf16 (wqkv|wproj|wfc1|wfc2 contiguous) ----
#define NW0 (3 * C_ * C_)
#define NW1 (C_ * C_)
#define NW2 (HID_ * C_)
#define NW3 (C_ * HID_)
__global__ __launch_bounds__(256)
void cvt_weights(const float* __restrict__ s0, const float* __restrict__ s1,
                 const float* __restrict__ s2, const float* __restrict__ s3,
                 short* __restrict__ dst)
{
    long i = ((long)blockIdx.x * 256 + threadIdx.x) * 4;
    const float* s; long off;
    if      (i < NW0)             { s = s0; off = i; }
    else if (i < NW0 + NW1)       { s = s1; off = i - NW0; }
    else if (i < NW0 + NW1 + NW2) { s = s2; off = i - NW0 - NW1; }
    else                          { s = s3; off = i - NW0 - NW1 - NW2; }
    float4 u = *(const float4*)(s + off);
    s4v o; o[0] = f2bf(u.x); o[1] = f2bf(u.y); o[2] = f2bf(u.z); o[3] = f2bf(u.w);
    *(s4v*)(dst + i) = o;
}

// ---------------- LayerNorm fp32 -> bf16 ----------------
__global__ __launch_bounds__(256)
void ln_bf16(const float* __restrict__ x, const float* __restrict__ g,
             const float* __restrict__ b, short* __restrict__ y)
{
    __shared__ float red[256];
    const long row = blockIdx.x;
    const float* xr = x + row * C_;
    short* yr = y + row * C_;
    const int t = threadIdx.x;
    float v0 = xr[t], v1 = xr[t + 256], v2 = xr[t + 512];
    red[t] = v0 + v1 + v2;
    __syncthreads();
    for (int o = 128; o > 0; o >>= 1) { if (t < o) red[t] += red[t + o]; __syncthreads(); }
    const float mu = red[0] * (1.0f / 768.0f);
    __syncthreads();
    const float d0 = v0 - mu, d1 = v1 - mu, d2 = v2 - mu;
    red[t] = d0 * d0 + d1 * d1 + d2 * d2;
    __syncthreads();
    for (int o = 128; o > 0; o >>= 1) { if (t < o) red[t] += red[t + o]; __syncthreads(); }
    const float rstd = rsqrtf(red[0] * (1.0f / 768.0f) + 1e-5f);
    yr[t]       = f2bf(d0 * rstd * g[t]       + b[t]);
    yr[t + 256] = f2bf(d1 * rstd * g[t + 256] + b[t + 256]);
    yr[t + 512] = f2bf(d2 * rstd * g[t + 512] + b[t + 512]);
}

// ---------------- MFMA GEMM: C = alpha*A@B^T (+bias)(+res)(gelu)(stats) ----------
// A: [M,K] bf16, B: [N,K] bf16. BK=64. LDS row = 64 bf16 = 8 chunks of 16B;
// chunk l at physical slot l ^ (row&7); staged via global_load_lds with
// pre-swizzled global source. Tile ids XCD-swizzled (T1).
template<int BM, int BN, int WGM, int WGN, bool OUTF32, bool ACT_GELU, bool STATS>
__global__ __launch_bounds__(256)
void gemm_mfma(const short* __restrict__ Ap, int lda, long sAb, long sAh,
               const short* __restrict__ Bp, int ldb, long sBb, long sBh,
               const float* __restrict__ bias,
               const float* __restrict__ res, int ldres,
               void* __restrict__ Cp, int ldc, long sCb, long sCh,
               float2* __restrict__ st,
               int K, float alpha)
{
    constexpr int FM = BM / (WGM * 16), FN = BN / (WGN * 16);
    __shared__ short As[BM * 64];
    __shared__ short Bs[BN * 64];
    const int tid = threadIdx.x;
    const int wid = tid >> 6, lane = tid & 63;
    const int z = blockIdx.z, zb = z / H_, zh = z - zb * H_;
    const int2 bxy = swz_xy();
    const int bx = bxy.x, by = bxy.y;
    const long m0 = (long)by * BM;
    const int  n0 = bx * BN;
    const short* Ab = Ap + zb * sAb + zh * sAh + m0 * lda;
    const short* Bb = Bp + zb * sBb + zh * sBh + (long)n0 * ldb;
    f32x4 acc[FM][FN] = {};
    const int wr = wid / WGN, wc = wid - wr * WGN;
    const int srow = lane >> 3;                  // row within 8-row group
    const int schunk = (lane & 7) ^ srow;        // pre-swizzled source chunk

    for (int k0 = 0; k0 < K; k0 += 64) {
        for (int g = wid; g < BM / 8; g += 4)
            gload16(Ab + (long)(g * 8 + srow) * lda + k0 + schunk * 8, &As[g * 512]);
        for (int g = wid; g < BN / 8; g += 4)
            gload16(Bb + (long)(g * 8 + srow) * ldb + k0 + schunk * 8, &Bs[g * 512]);
        __syncthreads();
        #pragma unroll
        for (int kk = 0; kk < 2; ++kk) {
            frag a[FM], b[FN];
            #pragma unroll
            for (int fm = 0; fm < FM; ++fm) {
                const int r = wr * FM * 16 + fm * 16 + (lane & 15);
                const int ph = (kk * 4 + (lane >> 4)) ^ (r & 7);
                a[fm] = *(const frag*)&As[r * 64 + ph * 8];
            }
            #pragma unroll
            for (int fn = 0; fn < FN; ++fn) {
                const int r = wc * FN * 16 + fn * 16 + (lane & 15);
                const int ph = (kk * 4 + (lane >> 4)) ^ (r & 7);
                b[fn] = *(const frag*)&Bs[r * 64 + ph * 8];
            }
            #pragma unroll
            for (int fm = 0; fm < FM; ++fm)
                #pragma unroll
                for (int fn = 0; fn < FN; ++fn)
                    acc[fm][fn] = __builtin_amdgcn_mfma_f32_16x16x32_bf16(a[fm], b[fn], acc[fm][fn], 0, 0, 0);
        }
        __syncthreads();
    }

    // ---- C store ----
    float* Cf = (float*)Cp; short* Cs = (short*)Cp;
    const long cbase = zb * sCb + zh * sCh;
    #pragma unroll
    for (int fm = 0; fm < FM; ++fm) {
        #pragma unroll
        for (int fn = 0; fn < FN; ++fn) {
            const long rg = m0 + wr * FM * 16 + fm * 16 + ((lane >> 4) * 4);
            const int  cg = n0 + wc * FN * 16 + fn * 16 + (lane & 15);
            const float bv = bias ? bias[cg] : 0.0f;
            #pragma unroll
            for (int q = 0; q < 4; ++q) {
                const long row = rg + q;
                float v = acc[fm][fn][q] * alpha + bv;
                if (res) v += res[row * (long)ldres + cg];
                if constexpr (ACT_GELU) v = gelu_exact(v);
                if constexpr (OUTF32) Cf[cbase + row * ldc + cg] = v;
                else                  Cs[cbase + row * ldc + cg] = f2bf(v);
            }
        }
    }

    // ---- softmax stats epilogue: per-row (tile-max, tile-expsum) of bf16-rounded S ----
    if constexpr (STATS) {
        float* sred = (float*)As;   // >= 2*BM floats
        float tmax[FM][4];
        #pragma unroll
        for (int fm = 0; fm < FM; ++fm)
            #pragma unroll
            for (int q = 0; q < 4; ++q) {
                float v = bfr(acc[fm][0][q] * alpha);
                #pragma unroll
                for (int fn = 1; fn < FN; ++fn) v = fmaxf(v, bfr(acc[fm][fn][q] * alpha));
                v = fmaxf(v, __shfl_xor(v, 1));
                v = fmaxf(v, __shfl_xor(v, 2));
                v = fmaxf(v, __shfl_xor(v, 4));
                v = fmaxf(v, __shfl_xor(v, 8));
                const int r = wr * FM * 16 + fm * 16 + (lane >> 4) * 4 + q;
                if ((lane & 15) == 0) sred[wc * BM + r] = v;
            }
        __syncthreads();
        #pragma unroll
        for (int fm = 0; fm < FM; ++fm)
            #pragma unroll
            for (int q = 0; q < 4; ++q) {
                const int r = wr * FM * 16 + fm * 16 + (lane >> 4) * 4 + q;
                tmax[fm][q] = fmaxf(sred[r], sred[BM + r]);
            }
        __syncthreads();
        #pragma unroll
        for (int fm = 0; fm < FM; ++fm)
            #pragma unroll
            for (int q = 0; q < 4; ++q) {
                float e = 0.0f;
                #pragma unroll
                for (int fn = 0; fn < FN; ++fn)
                    e += __expf(bfr(acc[fm][fn][q] * alpha) - tmax[fm][q]);
                e += __shfl_xor(e, 1);
                e += __shfl_xor(e, 2);
                e += __shfl_xor(e, 4);
                e += __shfl_xor(e, 8);
                const int r = wr * FM * 16 + fm * 16 + (lane >> 4) * 4 + q;
                if ((lane & 15) == 0) sred[wc * BM + r] = e;
            }
        __syncthreads();
        if (wc == 0) {
            #pragma unroll
            for (int fm = 0; fm < FM; ++fm)
                #pragma unroll
                for (int q = 0; q < 4; ++q) {
                    const int r = wr * FM * 16 + fm * 16 + (lane >> 4) * 4 + q;
                    if ((lane & 15) == 0) {
                        float2 o; o.x = tmax[fm][q]; o.y = sred[r] + sred[BM + r];
                        st[((long)z * N_ + m0 + r) * 8 + bx] = o;
                    }
                }
        }
    }
}

// ---------------- softmax(from stats) + head-mix + BN ----------------
// bf16 S -> fp32 attn (d_out) AND in-place bf16 mixed-P (overwrites S).
// One block per (b,n); thread t owns m = t*4..t*4+3 across all 12 heads.
// In-place safety: each thread reads all 12 h-planes into registers before
// writing any o-plane, and only touches its own (n, m-range) cells.
__global__ __launch_bounds__(256)
void smb2(short* __restrict__ S, const float2* __restrict__ st,
          float* __restrict__ attn,
          const float* __restrict__ cw, const float* __restrict__ cb,
          const float* __restrict__ bg, const float* __restrict__ bb,
          const float* __restrict__ brm, const float* __restrict__ brv)
{
    __shared__ float coef[H_][H_], baseA[H_], scA[H_], smx[H_], sinv[H_];
    const int t = threadIdx.x;
    const int bn = blockIdx.x;
    const int b = bn >> 10, n = bn & 1023;
    if (t < H_) {
        const float s = bg[t] * rsqrtf(brv[t] + 1e-5f);
        scA[t] = s;
        baseA[t] = (cb[t] - brm[t]) * s + bb[t];
    }
    __syncthreads();
    if (t < H_ * H_) coef[t / H_][t % H_] = cw[t] * scA[t / H_];
    if (t < H_) {
        const float2* sp = st + ((long)(b * H_ + t) * N_ + n) * 8;
        float2 sv[8];
        #pragma unroll
        for (int i = 0; i < 8; ++i) sv[i] = sp[i];
        float gm = sv[0].x;
        #pragma unroll
        for (int i = 1; i < 8; ++i) gm = fmaxf(gm, sv[i].x);
        float gs = 0.0f;
        #pragma unroll
        for (int i = 0; i < 8; ++i) gs += sv[i].y * __expf(sv[i].x - gm);
        smx[t] = gm;
        sinv[t] = 1.0f / gs;
    }
    __syncthreads();

    const long pstr = (long)N_ * N_;
    short*       sb = S    + (long)b * H_ * pstr + (long)n * N_ + t * 4;
    float*       ab = attn + (long)b * H_ * pstr + (long)n * N_ + t * 4;
    float4 p[H_];
    #pragma unroll
    for (int h = 0; h < H_; ++h) {
        const s4v sv = *(const s4v*)(sb + (long)h * pstr);
        const float gm = smx[h], gi = sinv[h];
        float4 e;
        e.x = __expf(b2f(sv[0]) - gm) * gi;
        e.y = __expf(b2f(sv[1]) - gm) * gi;
        e.z = __expf(b2f(sv[2]) - gm) * gi;
        e.w = __expf(b2f(sv[3]) - gm) * gi;
        p[h] = e;
    }
    #pragma unroll
    for (int o = 0; o < H_; ++o) {
        const float bse = baseA[o];
        float4 a; a.x = bse; a.y = bse; a.z = bse; a.w = bse;
        #pragma unroll
        for (int h = 0; h < H_; ++h) {
            const float w = coef[o][h];
            a.x += w * p[h].x; a.y += w * p[h].y;
            a.z += w * p[h].z; a.w += w * p[h].w;
        }
        *(float4*)(ab + (long)o * pstr) = a;
        s4v pb; pb[0] = f2bf(a.x); pb[1] = f2bf(a.y); pb[2] = f2bf(a.z); pb[3] = f2bf(a.w);
        *(s4v*)(sb + (long)o * pstr) = pb;
    }
}

// ---------------- v transpose: qkv bf16 [B*N,2304] -> vT [B*H][64][1024] ----------------
__global__ __launch_bounds__(256)
void vtrans(const short* __restrict__ qkv, short* __restrict__ vT)
{
    __shared__ short tile[64][72];
    const int bh = blockIdx.x;
    const int n0 = blockIdx.y * 64;
    const int b = bh / H_, h = bh - b * H_;
    const short* src = qkv + (long)b * N_ * (3 * C_) + 2 * C_ + h * D_;
    const int t = threadIdx.x;
    {
        const int r = t >> 2, c = (t & 3) * 16;
        const short* sp = src + (long)(n0 + r) * (3 * C_) + c;
        #pragma unroll
        for (int j = 0; j < 16; j++) tile[r][c + j] = sp[j];
    }
    __syncthreads();
    {
        const int d = t >> 2, c = (t & 3) * 16;
        short* dp = vT + (long)bh * (D_ * N_) + (long)d * N_ + n0 + c;
        #pragma unroll
        for (int j = 0; j < 16; j++) dp[j] = tile[c + j][d];
    }
}

// ---------------- launch ----------------
extern "C" void kernel_launch(void* const* d_in, const int* in_sizes, int n_in,
                              void* d_out, int out_size, void* d_ws, size_t ws_size,
                              hipStream_t stream)
{
    const float* inp    = (const float*)d_in[0];
    const float* ln1_g  = (const float*)d_in[1];
    const float* ln1_b  = (const float*)d_in[2];
    const float* qkv_w  = (const float*)d_in[3];
    const float* conv_w = (const float*)d_in[4];
    const float* conv_b = (const float*)d_in[5];
    const float* bn_g   = (const float*)d_in[6];
    const float* bn_b   = (const float*)d_in[7];
    const float* bn_rm  = (const float*)d_in[8];
    const float* bn_rv  = (const float*)d_in[9];
    const float* proj_w = (const float*)d_in[10];
    const float* proj_b = (const float*)d_in[11];
    const float* ln2_g  = (const float*)d_in[12];
    const float* ln2_b  = (const float*)d_in[13];
    const float* fc1_w  = (const float*)d_in[14];
    const float* fc1_b  = (const float*)d_in[15];
    const float* fc2_w  = (const float*)d_in[16];
    const float* fc2_b  = (const float*)d_in[17];

    float* outx = (float*)d_out;
    float* attn = outx + (long)M_ * C_;

    char* w = (char*)d_ws;
    short* wqkv  = (short*)w;  w += (long)NW0 * 2;
    short* wproj = (short*)w;  w += (long)NW1 * 2;
    short* wfc1  = (short*)w;  w += (long)NW2 * 2;
    short* wfc2  = (short*)w;  w += (long)NW3 * 2;
    short* xln   = (short*)w;  w += (long)M_ * C_ * 2;
    short* qkvb  = (short*)w;
    short* hbuf  = qkvb;       w += (long)M_ * HID_ * 2;   // max(qkv, h) region
    short* vT    = (short*)w;  w += (long)B_ * H_ * D_ * N_ * 2;
    short* Obf   = (short*)w;  w += (long)M_ * C_ * 2;
    float* xres  = (float*)w;  w += (long)M_ * C_ * 4;
    float2* st   = (float2*)w; w += (long)B_ * H_ * N_ * 8 * 8;
    short* Sbf   = (short*)w;  w += (long)B_ * H_ * N_ * N_ * 2;   // 201 MB; becomes P

    // weights -> bf16 (single fused launch; dst regions are contiguous)
    cvt_weights<<<(NW0 + NW1 + NW2 + NW3) / 1024, 256, 0, stream>>>(
        qkv_w, proj_w, fc1_w, fc2_w, wqkv);

    // 1) LN1 -> xln (bf16)
    ln_bf16<<<M_, 256, 0, stream>>>(inp, ln1_g, ln1_b, xln);

    // 2) qkv = xln @ qkv_w^T -> bf16 [8192,2304]
    gemm_mfma<128, 128, 2, 2, false, false, false><<<dim3(18, 64, 1), 256, 0, stream>>>(
        xln, C_, 0, 0, wqkv, C_, 0, 0, nullptr, nullptr, 0,
        qkvb, 3 * C_, 0, 0, nullptr, C_, 1.0f);

    // 3) vT = transpose(v)
    vtrans<<<dim3(B_ * H_, 16), 256, 0, stream>>>(qkvb, vT);

    // 4) S = 0.125 * q @ k^T -> bf16 Sbf + per-tile softmax stats
    gemm_mfma<128, 128, 2, 2, false, false, true><<<dim3(8, 8, 96), 256, 0, stream>>>(
        qkvb,      3 * C_, (long)N_ * 3 * C_, D_,
        qkvb + C_, 3 * C_, (long)N_ * 3 * C_, D_,
        nullptr, nullptr, 0,
        Sbf, N_, (long)H_ * N_ * N_, (long)N_ * N_, st, D_, 0.125f);

    // 5) softmax(stats) + mix + BN : Sbf -> fp32 attn (final) + in-place bf16 P
    smb2<<<M_, 256, 0, stream>>>(Sbf, st, attn, conv_w, conv_b, bn_g, bn_b, bn_rm, bn_rv);

    // 6) O = P @ v -> bf16 [B,N,C] layout (standard bf16 path on P)
    gemm_mfma<128, 64, 4, 1, false, false, false><<<dim3(1, 8, 96), 256, 0, stream>>>(
        Sbf, N_, (long)H_ * N_ * N_, (long)N_ * N_,
        vT, N_, (long)H_ * D_ * N_, (long)D_ * N_,
        nullptr, nullptr, 0,
        Obf, C_, (long)N_ * C_, D_, nullptr, N_, 1.0f);

    // 7) x = inputs + O @ proj_w^T + proj_b -> fp32
    gemm_mfma<128, 128, 2, 2, true, false, false><<<dim3(6, 64, 1), 256, 0, stream>>>(
        Obf, C_, 0, 0, wproj, C_, 0, 0, proj_b, inp, C_,
        xres, C_, 0, 0, nullptr, C_, 1.0f);

    // 8) LN2 -> xln (bf16, reuse)
    ln_bf16<<<M_, 256, 0, stream>>>(xres, ln2_g, ln2_b, xln);

    // 9) h = gelu(xln @ fc1_w^T + fc1_b) -> bf16
    gemm_mfma<128, 128, 2, 2, false, true, false><<<dim3(24, 64, 1), 256, 0, stream>>>(
        xln, C_, 0, 0, wfc1, C_, 0, 0, fc1_b, nullptr, 0,
        hbuf, HID_, 0, 0, nullptr, C_, 1.0f);

    // 10) out = x + h @ fc2_w^T + fc2_b -> fp32
    gemm_mfma<128, 128, 2, 2, true, false, false><<<dim3(6, 64, 1), 256, 0, stream>>>(
        hbuf, HID_, 0, 0, wfc2, HID_, 0, 0, fc2_b, xres, C_,
        outx, C_, 0, 0, nullptr, HID_, 1.0f);
}

// Round 6
// 544.973 us; speedup vs baseline: 1.4941x; 1.1222x over previous
//
#include <hip/hip_runtime.h>
#include <cmath>

#define B_   8
#define N_   1024
#define C_   768
#define H_   12
#define D_   64
#define HID_ 3072
#define M_   8192   // B_*N_

using frag  = __attribute__((ext_vector_type(8))) short;   // 8 bf16
using f32x4 = __attribute__((ext_vector_type(4))) float;
using s4v   = __attribute__((ext_vector_type(4))) short;

__device__ __forceinline__ short f2bf(float x) {
    union { float f; unsigned u; } v; v.f = x;
    unsigned r = (v.u + 0x7FFFu + ((v.u >> 16) & 1u)) >> 16;  // RNE
    return (short)r;
}
__device__ __forceinline__ float gelu_exact(float x) {
    return 0.5f * x * (1.0f + erff(x * 0.70710678118654752f));
}
__device__ __forceinline__ void gload16(const void* g, void* l) {
    __builtin_amdgcn_global_load_lds(
        (const __attribute__((address_space(1))) void*)g,
        (__attribute__((address_space(3))) void*)l, 16, 0, 0);
}

// Bijective XCD-aware tile swizzle (m204).
__device__ __forceinline__ int2 swz_xy() {
    const int gx = gridDim.x;
    const int nwg = gx * gridDim.y;
    const int orig = blockIdx.y * gx + blockIdx.x;
    const int q = nwg >> 3, r = nwg & 7;
    const int xcd = orig & 7;
    const int base = (xcd < r) ? xcd * (q + 1) : r * (q + 1) + (xcd - r) * q;
    const int wgid = base + (orig >> 3);
    int2 v; v.x = wgid % gx; v.y = wgid / gx;
    return v;
}

// ---------------- fused weights fp32 -> bf16 ----------------
#define NW0 (3 * C_ * C_)
#define NW1 (C_ * C_)
#define NW2 (HID_ * C_)
#define NW3 (C_ * HID_)
__global__ __launch_bounds__(256)
void cvt_weights(const float* __restrict__ s0, const float* __restrict__ s1,
                 const float* __restrict__ s2, const float* __restrict__ s3,
                 short* __restrict__ dst)
{
    long i = ((long)blockIdx.x * 256 + threadIdx.x) * 4;
    const float* s; long off;
    if      (i < NW0)             { s = s0; off = i; }
    else if (i < NW0 + NW1)       { s = s1; off = i - NW0; }
    else if (i < NW0 + NW1 + NW2) { s = s2; off = i - NW0 - NW1; }
    else                          { s = s3; off = i - NW0 - NW1 - NW2; }
    float4 u = *(const float4*)(s + off);
    s4v o; o[0] = f2bf(u.x); o[1] = f2bf(u.y); o[2] = f2bf(u.z); o[3] = f2bf(u.w);
    *(s4v*)(dst + i) = o;
}

// ---------------- LayerNorm fp32 -> bf16 ----------------
__global__ __launch_bounds__(256)
void ln_bf16(const float* __restrict__ x, const float* __restrict__ g,
             const float* __restrict__ b, short* __restrict__ y)
{
    __shared__ float red[256];
    const long row = blockIdx.x;
    const float* xr = x + row * C_;
    short* yr = y + row * C_;
    const int t = threadIdx.x;
    float v0 = xr[t], v1 = xr[t + 256], v2 = xr[t + 512];
    red[t] = v0 + v1 + v2;
    __syncthreads();
    for (int o = 128; o > 0; o >>= 1) { if (t < o) red[t] += red[t + o]; __syncthreads(); }
    const float mu = red[0] * (1.0f / 768.0f);
    __syncthreads();
    const float d0 = v0 - mu, d1 = v1 - mu, d2 = v2 - mu;
    red[t] = d0 * d0 + d1 * d1 + d2 * d2;
    __syncthreads();
    for (int o = 128; o > 0; o >>= 1) { if (t < o) red[t] += red[t + o]; __syncthreads(); }
    const float rstd = rsqrtf(red[0] * (1.0f / 768.0f) + 1e-5f);
    yr[t]       = f2bf(d0 * rstd * g[t]       + b[t]);
    yr[t + 256] = f2bf(d1 * rstd * g[t + 256] + b[t + 256]);
    yr[t + 512] = f2bf(d2 * rstd * g[t + 512] + b[t + 512]);
}

// ---------------- MFMA GEMM: C = alpha*A@B^T (+bias)(+res)(gelu)(stats) ----------
// A: [M,K] bf16 (or fp32 reg-staged if AF32). B: [N,K] bf16. BK=64.
// LDS row = 64 bf16 = 8 chunks of 16B; chunk l at physical slot l ^ (row&7).
// GMODE 0: (x,y,z) grid with m204 xy-swizzle.  GMODE 1: 1-D grid, z-folded
// (wg = swz(bid); by = wg&7, z = wg>>3, bx = 0) for per-XCD batch locality.
template<int BM, int BN, int WGM, int WGN, bool AF32, bool OUTF32,
         bool ACT_GELU, bool STATS, bool CW, bool NTC, int GMODE>
__global__ __launch_bounds__(256)
void gemm_mfma(const void* __restrict__ Ap, int lda, long sAb, long sAh,
               const short* __restrict__ Bp, int ldb, long sBb, long sBh,
               const float* __restrict__ bias,
               const float* __restrict__ res, int ldres,
               void* __restrict__ Cp, int ldc, long sCb, long sCh,
               float2* __restrict__ st,
               int K, float alpha)
{
    constexpr int FM = BM / (WGM * 16), FN = BN / (WGN * 16);
    __shared__ short As[BM * 64];
    __shared__ short Bs[BN * 64];
    const int tid = threadIdx.x;
    const int wid = tid >> 6, lane = tid & 63;
    int bx, by, z;
    if constexpr (GMODE == 1) {
        const int nwg = gridDim.x;
        const int qc = nwg >> 3;
        const int wg = (blockIdx.x & 7) * qc + (blockIdx.x >> 3);
        bx = 0; by = wg & 7; z = wg >> 3;
    } else {
        int2 v = swz_xy(); bx = v.x; by = v.y; z = blockIdx.z;
    }
    const int zb = z / H_, zh = z - zb * H_;
    const long m0 = (long)by * BM;
    const int  n0 = bx * BN;
    const short* Bb = Bp + zb * sBb + zh * sBh + (long)n0 * ldb;
    const short* Abh = nullptr; const float* Afh = nullptr;
    if constexpr (AF32) Afh = (const float*)Ap + zb * sAb + zh * sAh + m0 * lda;
    else                Abh = (const short*)Ap + zb * sAb + zh * sAh + m0 * lda;
    f32x4 acc[FM][FN] = {};
    const int wr = wid / WGN, wc = wid - wr * WGN;
    const int srow = lane >> 3;                  // row within 8-row group
    const int schunk = (lane & 7) ^ srow;        // pre-swizzled source chunk

    for (int k0 = 0; k0 < K; k0 += 64) {
        if constexpr (!AF32) {
            for (int g = wid; g < BM / 8; g += 4)
                gload16(Abh + (long)(g * 8 + srow) * lda + k0 + schunk * 8, &As[g * 512]);
        } else {
            // reg-stage 128x64 fp32 -> bf16 swizzled LDS (BM must be 128)
            const int r = tid >> 1, h2 = tid & 1;
            const float* sp = Afh + (long)r * lda + k0 + h2 * 32;
            #pragma unroll
            for (int j = 0; j < 4; ++j) {
                float4 u0 = *(const float4*)(sp + j * 8);
                float4 u1 = *(const float4*)(sp + j * 8 + 4);
                frag w;
                w[0] = f2bf(u0.x); w[1] = f2bf(u0.y); w[2] = f2bf(u0.z); w[3] = f2bf(u0.w);
                w[4] = f2bf(u1.x); w[5] = f2bf(u1.y); w[6] = f2bf(u1.z); w[7] = f2bf(u1.w);
                *(frag*)&As[r * 64 + ((h2 * 4 + j) ^ (r & 7)) * 8] = w;
            }
        }
        for (int g = wid; g < BN / 8; g += 4)
            gload16(Bb + (long)(g * 8 + srow) * ldb + k0 + schunk * 8, &Bs[g * 512]);
        __syncthreads();
        #pragma unroll
        for (int kk = 0; kk < 2; ++kk) {
            frag a[FM], b[FN];
            #pragma unroll
            for (int fm = 0; fm < FM; ++fm) {
                const int r = wr * FM * 16 + fm * 16 + (lane & 15);
                const int ph = (kk * 4 + (lane >> 4)) ^ (r & 7);
                a[fm] = *(const frag*)&As[r * 64 + ph * 8];
            }
            #pragma unroll
            for (int fn = 0; fn < FN; ++fn) {
                const int r = wc * FN * 16 + fn * 16 + (lane & 15);
                const int ph = (kk * 4 + (lane >> 4)) ^ (r & 7);
                b[fn] = *(const frag*)&Bs[r * 64 + ph * 8];
            }
            #pragma unroll
            for (int fm = 0; fm < FM; ++fm)
                #pragma unroll
                for (int fn = 0; fn < FN; ++fn)
                    acc[fm][fn] = __builtin_amdgcn_mfma_f32_16x16x32_bf16(a[fm], b[fn], acc[fm][fn], 0, 0, 0);
        }
        __syncthreads();
    }

    // ---- C store ----
    if constexpr (CW) {
        float* Cf = (float*)Cp; short* Cs = (short*)Cp;
        const long cbase = zb * sCb + zh * sCh;
        #pragma unroll
        for (int fm = 0; fm < FM; ++fm) {
            #pragma unroll
            for (int fn = 0; fn < FN; ++fn) {
                const long rg = m0 + wr * FM * 16 + fm * 16 + ((lane >> 4) * 4);
                const int  cg = n0 + wc * FN * 16 + fn * 16 + (lane & 15);
                const float bv = bias ? bias[cg] : 0.0f;
                #pragma unroll
                for (int q = 0; q < 4; ++q) {
                    const long row = rg + q;
                    float v = acc[fm][fn][q] * alpha + bv;
                    if (res) v += res[row * (long)ldres + cg];
                    if constexpr (ACT_GELU) v = gelu_exact(v);
                    if constexpr (OUTF32) {
                        if constexpr (NTC) __builtin_nontemporal_store(v, &Cf[cbase + row * ldc + cg]);
                        else               Cf[cbase + row * ldc + cg] = v;
                    } else {
                        Cs[cbase + row * ldc + cg] = f2bf(v);
                    }
                }
            }
        }
    }

    // ---- softmax stats epilogue: per-row (tile-max, tile-expsum), raw fp32 ----
    if constexpr (STATS) {
        float* sred = (float*)As;   // >= 2*BM floats
        float tmax[FM][4];
        #pragma unroll
        for (int fm = 0; fm < FM; ++fm)
            #pragma unroll
            for (int q = 0; q < 4; ++q) {
                float v = acc[fm][0][q];
                #pragma unroll
                for (int fn = 1; fn < FN; ++fn) v = fmaxf(v, acc[fm][fn][q]);
                v *= alpha;
                v = fmaxf(v, __shfl_xor(v, 1));
                v = fmaxf(v, __shfl_xor(v, 2));
                v = fmaxf(v, __shfl_xor(v, 4));
                v = fmaxf(v, __shfl_xor(v, 8));
                const int r = wr * FM * 16 + fm * 16 + (lane >> 4) * 4 + q;
                if ((lane & 15) == 0) sred[wc * BM + r] = v;
            }
        __syncthreads();
        #pragma unroll
        for (int fm = 0; fm < FM; ++fm)
            #pragma unroll
            for (int q = 0; q < 4; ++q) {
                const int r = wr * FM * 16 + fm * 16 + (lane >> 4) * 4 + q;
                tmax[fm][q] = fmaxf(sred[r], sred[BM + r]);
            }
        __syncthreads();
        #pragma unroll
        for (int fm = 0; fm < FM; ++fm)
            #pragma unroll
            for (int q = 0; q < 4; ++q) {
                float e = 0.0f;
                #pragma unroll
                for (int fn = 0; fn < FN; ++fn)
                    e += __expf(acc[fm][fn][q] * alpha - tmax[fm][q]);
                e += __shfl_xor(e, 1);
                e += __shfl_xor(e, 2);
                e += __shfl_xor(e, 4);
                e += __shfl_xor(e, 8);
                const int r = wr * FM * 16 + fm * 16 + (lane >> 4) * 4 + q;
                if ((lane & 15) == 0) sred[wc * BM + r] = e;
            }
        __syncthreads();
        if (wc == 0) {
            #pragma unroll
            for (int fm = 0; fm < FM; ++fm)
                #pragma unroll
                for (int q = 0; q < 4; ++q) {
                    const int r = wr * FM * 16 + fm * 16 + (lane >> 4) * 4 + q;
                    if ((lane & 15) == 0) {
                        float2 o; o.x = tmax[fm][q]; o.y = sred[r] + sred[BM + r];
                        st[((long)z * N_ + m0 + r) * 8 + bx] = o;
                    }
                }
        }
    }
}

// ---------------- fused QK^T-recompute + softmax(stats) + head-mix + BN -------
// Block = 16 q-rows x 64 m-cols x all 12 heads, 256 thr / 4 waves.
// S recomputed via MFMA (bitwise == pass-1 values); exp/mix in registers;
// writes final fp32 attn with nontemporal stores. No S materialization.
__global__ __launch_bounds__(256)
void qksm(const short* __restrict__ qkvb, const float2* __restrict__ st,
          float* __restrict__ attn,
          const float* __restrict__ cw, const float* __restrict__ cb,
          const float* __restrict__ bg, const float* __restrict__ bb,
          const float* __restrict__ brm, const float* __restrict__ brv)
{
    __shared__ short qs[H_ * 16 * 64];     // 24 KB: q rows for all heads
    __shared__ short ks[2][64 * 64];       // 16 KB: per-head k tile, dbuf
    __shared__ float smx[H_][16], sinv[H_][16];
    __shared__ float coef[H_][H_], baseA[H_], scA[H_];
    const int tid = threadIdx.x, wid = tid >> 6, lane = tid & 63;

    // 1-D m204 swizzle: 8192 wgs, 1024/XCD -> XCD x owns batch x (q,k L2-hot)
    const int wg = (blockIdx.x & 7) * 1024 + (blockIdx.x >> 3);
    const int b = wg >> 10, nblk = (wg >> 4) & 63, mblk = wg & 15;
    const int n0 = nblk * 16, m0 = mblk * 64;

    if (tid < H_) {
        const float s = bg[tid] * rsqrtf(brv[tid] + 1e-5f);
        scA[tid] = s;
        baseA[tid] = (cb[tid] - brm[tid]) * s + bb[tid];
    }
    __syncthreads();
    if (tid < H_ * H_) coef[tid / H_][tid % H_] = cw[tid] * scA[tid / H_];
    if (tid < 192) {
        const int h = tid >> 4, r = tid & 15;
        const float2* sp = st + ((long)(b * H_ + h) * N_ + n0 + r) * 8;
        float2 sv[8];
        #pragma unroll
        for (int i = 0; i < 8; ++i) sv[i] = sp[i];
        float gm = sv[0].x;
        #pragma unroll
        for (int i = 1; i < 8; ++i) gm = fmaxf(gm, sv[i].x);
        float gs = 0.0f;
        #pragma unroll
        for (int i = 0; i < 8; ++i) gs += sv[i].y * __expf(sv[i].x - gm);
        smx[h][r] = gm;
        sinv[h][r] = 1.0f / gs;
    }
    __syncthreads();   // publish smx/sinv/coef; stats loads retired

    // stage q (all 12 heads x 16 rows) + k tile for head 0
    const int srow = lane >> 3, schunk = (lane & 7) ^ srow;
    const short* qbase = qkvb + (long)(b * N_ + n0) * (3 * C_);
    for (int g = wid; g < 24; g += 4) {
        const int fr = g * 8 + srow;   // fr = h*16 + n
        gload16(qbase + (long)(fr & 15) * (3 * C_) + (fr >> 4) * 64 + schunk * 8,
                &qs[g * 512]);
    }
    const short* kbase = qkvb + C_ + (long)(b * N_ + m0) * (3 * C_);
    for (int g = wid; g < 8; g += 4) {
        const int fr = g * 8 + srow;
        gload16(kbase + (long)fr * (3 * C_) + schunk * 8, &ks[0][g * 512]);
    }

    float macc[H_][4] = {};
    const int rowb = (lane >> 4) * 4;
    const int colw = wid * 16 + (lane & 15);

    for (int h = 0; h < H_; ++h) {
        asm volatile("s_waitcnt vmcnt(0)" ::: "memory");
        __builtin_amdgcn_sched_barrier(0);
        __builtin_amdgcn_s_barrier();
        // stage next head's k tile (safe: all waves past barrier => prior
        // reads of this buffer are retired); DMA overlaps this head's compute
        if (h < H_ - 1) {
            for (int g = wid; g < 8; g += 4) {
                const int fr = g * 8 + srow;
                gload16(kbase + (long)fr * (3 * C_) + (h + 1) * 64 + schunk * 8,
                        &ks[(h + 1) & 1][g * 512]);
            }
        }
        f32x4 acc = {};
        const int afr = h * 16 + (lane & 15);
        const int bfr = colw;
        #pragma unroll
        for (int kk = 0; kk < 2; ++kk) {
            const frag a  = *(const frag*)&qs[afr * 64 + (((kk * 4 + (lane >> 4)) ^ (afr & 7))) * 8];
            const frag bv = *(const frag*)&ks[h & 1][bfr * 64 + (((kk * 4 + (lane >> 4)) ^ (bfr & 7))) * 8];
            acc = __builtin_amdgcn_mfma_f32_16x16x32_bf16(a, bv, acc, 0, 0, 0);
        }
        #pragma unroll
        for (int q = 0; q < 4; ++q) {
            const float e = __expf(acc[q] * 0.125f - smx[h][rowb + q]) * sinv[h][rowb + q];
            #pragma unroll
            for (int o = 0; o < H_; ++o) macc[o][q] += coef[o][h] * e;
        }
    }

    #pragma unroll
    for (int o = 0; o < H_; ++o) {
        float* ap = attn + ((long)(b * H_ + o) << 20) + ((long)(n0 + rowb) << 10) + m0 + colw;
        #pragma unroll
        for (int q = 0; q < 4; ++q)
            __builtin_nontemporal_store(macc[o][q] + baseA[o], ap + ((long)q << 10));
    }
}

// ---------------- v transpose: qkv bf16 [B*N,2304] -> vT [B*H][64][1024] -----
__global__ __launch_bounds__(256)
void vtrans(const short* __restrict__ qkv, short* __restrict__ vT)
{
    __shared__ short tile[64][72];
    const int bh = blockIdx.x;
    const int n0 = blockIdx.y * 64;
    const int b = bh / H_, h = bh - b * H_;
    const short* src = qkv + (long)b * N_ * (3 * C_) + 2 * C_ + h * D_;
    const int t = threadIdx.x;
    {
        const int r = t >> 2, c = (t & 3) * 16;
        const short* sp = src + (long)(n0 + r) * (3 * C_) + c;
        #pragma unroll
        for (int j = 0; j < 16; j++) tile[r][c + j] = sp[j];
    }
    __syncthreads();
    {
        const int d = t >> 2, c = (t & 3) * 16;
        short* dp = vT + (long)bh * (D_ * N_) + (long)d * N_ + n0 + c;
        #pragma unroll
        for (int j = 0; j < 16; j++) dp[j] = tile[c + j][d];
    }
}

// ---------------- launch ----------------
extern "C" void kernel_launch(void* const* d_in, const int* in_sizes, int n_in,
                              void* d_out, int out_size, void* d_ws, size_t ws_size,
                              hipStream_t stream)
{
    const float* inp    = (const float*)d_in[0];
    const float* ln1_g  = (const float*)d_in[1];
    const float* ln1_b  = (const float*)d_in[2];
    const float* qkv_w  = (const float*)d_in[3];
    const float* conv_w = (const float*)d_in[4];
    const float* conv_b = (const float*)d_in[5];
    const float* bn_g   = (const float*)d_in[6];
    const float* bn_b   = (const float*)d_in[7];
    const float* bn_rm  = (const float*)d_in[8];
    const float* bn_rv  = (const float*)d_in[9];
    const float* proj_w = (const float*)d_in[10];
    const float* proj_b = (const float*)d_in[11];
    const float* ln2_g  = (const float*)d_in[12];
    const float* ln2_b  = (const float*)d_in[13];
    const float* fc1_w  = (const float*)d_in[14];
    const float* fc1_b  = (const float*)d_in[15];
    const float* fc2_w  = (const float*)d_in[16];
    const float* fc2_b  = (const float*)d_in[17];

    float* outx = (float*)d_out;
    float* attn = outx + (long)M_ * C_;

    char* w = (char*)d_ws;
    short* wqkv  = (short*)w;  w += (long)NW0 * 2;
    short* wproj = (short*)w;  w += (long)NW1 * 2;
    short* wfc1  = (short*)w;  w += (long)NW2 * 2;
    short* wfc2  = (short*)w;  w += (long)NW3 * 2;
    short* xln   = (short*)w;  w += (long)M_ * C_ * 2;
    short* qkvb  = (short*)w;
    short* hbuf  = qkvb;       w += (long)M_ * HID_ * 2;   // max(qkv, h) region
    short* vT    = (short*)w;  w += (long)B_ * H_ * D_ * N_ * 2;
    short* Obf   = (short*)w;  w += (long)M_ * C_ * 2;
    float* xres  = (float*)w;  w += (long)M_ * C_ * 4;
    float2* st   = (float2*)w; w += (long)B_ * H_ * N_ * 8 * 8;

    // weights -> bf16 (single fused launch; dst regions are contiguous)
    cvt_weights<<<(NW0 + NW1 + NW2 + NW3) / 1024, 256, 0, stream>>>(
        qkv_w, proj_w, fc1_w, fc2_w, wqkv);

    // 1) LN1 -> xln (bf16)
    ln_bf16<<<M_, 256, 0, stream>>>(inp, ln1_g, ln1_b, xln);

    // 2) qkv = xln @ qkv_w^T -> bf16 [8192,2304]
    gemm_mfma<128, 128, 2, 2, false, false, false, false, true, false, 0>
        <<<dim3(18, 64, 1), 256, 0, stream>>>(
        xln, C_, 0, 0, wqkv, C_, 0, 0, nullptr, nullptr, 0,
        qkvb, 3 * C_, 0, 0, nullptr, C_, 1.0f);

    // 3) vT = transpose(v)
    vtrans<<<dim3(B_ * H_, 16), 256, 0, stream>>>(qkvb, vT);

    // 4) pass-1: QK^T stats only (no C write) -> st
    gemm_mfma<128, 128, 2, 2, false, false, false, true, false, false, 0>
        <<<dim3(8, 8, 96), 256, 0, stream>>>(
        qkvb,      3 * C_, (long)N_ * 3 * C_, D_,
        qkvb + C_, 3 * C_, (long)N_ * 3 * C_, D_,
        nullptr, nullptr, 0,
        nullptr, N_, 0, 0, st, D_, 0.125f);

    // 5) pass-2: fused QK^T recompute + softmax + mix + BN -> fp32 attn (final)
    qksm<<<8192, 256, 0, stream>>>(qkvb, st, attn,
                                   conv_w, conv_b, bn_g, bn_b, bn_rm, bn_rv);

    // 6) O = attn @ v -> bf16 [B,N,C] (AF32 reg-stage A; z-folded 1-D swizzle)
    gemm_mfma<128, 64, 4, 1, true, false, false, false, true, false, 1>
        <<<dim3(768, 1, 1), 256, 0, stream>>>(
        attn, N_, (long)H_ * N_ * N_, (long)N_ * N_,
        vT, N_, (long)H_ * D_ * N_, (long)D_ * N_,
        nullptr, nullptr, 0,
        Obf, C_, (long)N_ * C_, D_, nullptr, N_, 1.0f);

    // 7) x = inputs + O @ proj_w^T + proj_b -> fp32 (BN=64 grid: 768 blocks)
    gemm_mfma<128, 64, 4, 1, false, true, false, false, true, false, 0>
        <<<dim3(12, 64, 1), 256, 0, stream>>>(
        Obf, C_, 0, 0, wproj, C_, 0, 0, proj_b, inp, C_,
        xres, C_, 0, 0, nullptr, C_, 1.0f);

    // 8) LN2 -> xln (bf16, reuse)
    ln_bf16<<<M_, 256, 0, stream>>>(xres, ln2_g, ln2_b, xln);

    // 9) h = gelu(xln @ fc1_w^T + fc1_b) -> bf16
    gemm_mfma<128, 128, 2, 2, false, false, true, false, true, false, 0>
        <<<dim3(24, 64, 1), 256, 0, stream>>>(
        xln, C_, 0, 0, wfc1, C_, 0, 0, fc1_b, nullptr, 0,
        hbuf, HID_, 0, 0, nullptr, C_, 1.0f);

    // 10) out = x + h @ fc2_w^T + fc2_b -> fp32 NT (BN=64 grid: 768 blocks)
    gemm_mfma<128, 64, 4, 1, false, true, false, false, true, true, 0>
        <<<dim3(12, 64, 1), 256, 0, stream>>>(
        hbuf, HID_, 0, 0, wfc2, HID_, 0, 0, fc2_b, xres, C_,
        outx, C_, 0, 0, nullptr, HID_, 1.0f);
}

// Round 8
// 542.347 us; speedup vs baseline: 1.5014x; 1.0048x over previous
//
#include <hip/hip_runtime.h>
#include <cmath>

#define B_   8
#define N_   1024
#define C_   768
#define H_   12
#define D_   64
#define HID_ 3072
#define M_   8192   // B_*N_

using frag  = __attribute__((ext_vector_type(8))) short;   // 8 bf16
using f32x4 = __attribute__((ext_vector_type(4))) float;
using s4v   = __attribute__((ext_vector_type(4))) short;

__device__ __forceinline__ short f2bf(float x) {
    union { float f; unsigned u; } v; v.f = x;
    unsigned r = (v.u + 0x7FFFu + ((v.u >> 16) & 1u)) >> 16;  // RNE
    return (short)r;
}
__device__ __forceinline__ float gelu_exact(float x) {
    return 0.5f * x * (1.0f + erff(x * 0.70710678118654752f));
}
__device__ __forceinline__ void gload16(const void* g, void* l) {
    __builtin_amdgcn_global_load_lds(
        (const __attribute__((address_space(1))) void*)g,
        (__attribute__((address_space(3))) void*)l, 16, 0, 0);
}

// Bijective XCD-aware tile swizzle (m204).
__device__ __forceinline__ int2 swz_xy() {
    const int gx = gridDim.x;
    const int nwg = gx * gridDim.y;
    const int orig = blockIdx.y * gx + blockIdx.x;
    const int q = nwg >> 3, r = nwg & 7;
    const int xcd = orig & 7;
    const int base = (xcd < r) ? xcd * (q + 1) : r * (q + 1) + (xcd - r) * q;
    const int wgid = base + (orig >> 3);
    int2 v; v.x = wgid % gx; v.y = wgid / gx;
    return v;
}

// ---------------- fused weights fp32 -> bf16 ----------------
#define NW0 (3 * C_ * C_)
#define NW1 (C_ * C_)
#define NW2 (HID_ * C_)
#define NW3 (C_ * HID_)
__global__ __launch_bounds__(256)
void cvt_weights(const float* __restrict__ s0, const float* __restrict__ s1,
                 const float* __restrict__ s2, const float* __restrict__ s3,
                 short* __restrict__ dst)
{
    long i = ((long)blockIdx.x * 256 + threadIdx.x) * 4;
    const float* s; long off;
    if      (i < NW0)             { s = s0; off = i; }
    else if (i < NW0 + NW1)       { s = s1; off = i - NW0; }
    else if (i < NW0 + NW1 + NW2) { s = s2; off = i - NW0 - NW1; }
    else                          { s = s3; off = i - NW0 - NW1 - NW2; }
    float4 u = *(const float4*)(s + off);
    s4v o; o[0] = f2bf(u.x); o[1] = f2bf(u.y); o[2] = f2bf(u.z); o[3] = f2bf(u.w);
    *(s4v*)(dst + i) = o;
}

// ---------------- LayerNorm fp32 -> bf16 ----------------
__global__ __launch_bounds__(256)
void ln_bf16(const float* __restrict__ x, const float* __restrict__ g,
             const float* __restrict__ b, short* __restrict__ y)
{
    __shared__ float red[256];
    const long row = blockIdx.x;
    const float* xr = x + row * C_;
    short* yr = y + row * C_;
    const int t = threadIdx.x;
    float v0 = xr[t], v1 = xr[t + 256], v2 = xr[t + 512];
    red[t] = v0 + v1 + v2;
    __syncthreads();
    for (int o = 128; o > 0; o >>= 1) { if (t < o) red[t] += red[t + o]; __syncthreads(); }
    const float mu = red[0] * (1.0f / 768.0f);
    __syncthreads();
    const float d0 = v0 - mu, d1 = v1 - mu, d2 = v2 - mu;
    red[t] = d0 * d0 + d1 * d1 + d2 * d2;
    __syncthreads();
    for (int o = 128; o > 0; o >>= 1) { if (t < o) red[t] += red[t + o]; __syncthreads(); }
    const float rstd = rsqrtf(red[0] * (1.0f / 768.0f) + 1e-5f);
    yr[t]       = f2bf(d0 * rstd * g[t]       + b[t]);
    yr[t + 256] = f2bf(d1 * rstd * g[t + 256] + b[t + 256]);
    yr[t + 512] = f2bf(d2 * rstd * g[t + 512] + b[t + 512]);
}

// ---------------- MFMA GEMM: C = alpha*A@B^T (+bias)(+res)(gelu)(stats) ----------
// A: [M,K] bf16. B: [N,K] bf16. BK=64. LDS row = 64 bf16 = 8 chunks of 16B;
// chunk l at physical slot l ^ (row&7); staged via global_load_lds with
// pre-swizzled global source. GMODE 0: (x,y,z) grid, m204 xy-swizzle.
// GMODE 1: 1-D grid, z-folded (by = wg&7, z = wg>>3) for per-XCD z locality.
template<int BM, int BN, int WGM, int WGN, bool OUTF32,
         bool ACT_GELU, bool STATS, bool CW, bool NTC, int GMODE>
__global__ __launch_bounds__(256)
void gemm_mfma(const short* __restrict__ Ap, int lda, long sAb, long sAh,
               const short* __restrict__ Bp, int ldb, long sBb, long sBh,
               const float* __restrict__ bias,
               const float* __restrict__ res, int ldres,
               void* __restrict__ Cp, int ldc, long sCb, long sCh,
               float2* __restrict__ st,
               int K, float alpha)
{
    constexpr int FM = BM / (WGM * 16), FN = BN / (WGN * 16);
    __shared__ short As[BM * 64];
    __shared__ short Bs[BN * 64];
    const int tid = threadIdx.x;
    const int wid = tid >> 6, lane = tid & 63;
    int bx, by, z;
    if constexpr (GMODE == 1) {
        const int nwg = gridDim.x;
        const int qc = nwg >> 3;
        const int wg = (blockIdx.x & 7) * qc + (blockIdx.x >> 3);
        bx = 0; by = wg & 7; z = wg >> 3;
    } else {
        int2 v = swz_xy(); bx = v.x; by = v.y; z = blockIdx.z;
    }
    const int zb = z / H_, zh = z - zb * H_;
    const long m0 = (long)by * BM;
    const int  n0 = bx * BN;
    const short* Ab = Ap + zb * sAb + zh * sAh + m0 * lda;
    const short* Bb = Bp + zb * sBb + zh * sBh + (long)n0 * ldb;
    f32x4 acc[FM][FN] = {};
    const int wr = wid / WGN, wc = wid - wr * WGN;
    const int srow = lane >> 3;                  // row within 8-row group
    const int schunk = (lane & 7) ^ srow;        // pre-swizzled source chunk

    for (int k0 = 0; k0 < K; k0 += 64) {
        for (int g = wid; g < BM / 8; g += 4)
            gload16(Ab + (long)(g * 8 + srow) * lda + k0 + schunk * 8, &As[g * 512]);
        for (int g = wid; g < BN / 8; g += 4)
            gload16(Bb + (long)(g * 8 + srow) * ldb + k0 + schunk * 8, &Bs[g * 512]);
        __syncthreads();
        #pragma unroll
        for (int kk = 0; kk < 2; ++kk) {
            frag a[FM], b[FN];
            #pragma unroll
            for (int fm = 0; fm < FM; ++fm) {
                const int r = wr * FM * 16 + fm * 16 + (lane & 15);
                const int ph = (kk * 4 + (lane >> 4)) ^ (r & 7);
                a[fm] = *(const frag*)&As[r * 64 + ph * 8];
            }
            #pragma unroll
            for (int fn = 0; fn < FN; ++fn) {
                const int r = wc * FN * 16 + fn * 16 + (lane & 15);
                const int ph = (kk * 4 + (lane >> 4)) ^ (r & 7);
                b[fn] = *(const frag*)&Bs[r * 64 + ph * 8];
            }
            #pragma unroll
            for (int fm = 0; fm < FM; ++fm)
                #pragma unroll
                for (int fn = 0; fn < FN; ++fn)
                    acc[fm][fn] = __builtin_amdgcn_mfma_f32_16x16x32_bf16(a[fm], b[fn], acc[fm][fn], 0, 0, 0);
        }
        __syncthreads();
    }

    // ---- C store ----
    if constexpr (CW) {
        float* Cf = (float*)Cp; short* Cs = (short*)Cp;
        const long cbase = zb * sCb + zh * sCh;
        #pragma unroll
        for (int fm = 0; fm < FM; ++fm) {
            #pragma unroll
            for (int fn = 0; fn < FN; ++fn) {
                const long rg = m0 + wr * FM * 16 + fm * 16 + ((lane >> 4) * 4);
                const int  cg = n0 + wc * FN * 16 + fn * 16 + (lane & 15);
                const float bv = bias ? bias[cg] : 0.0f;
                #pragma unroll
                for (int q = 0; q < 4; ++q) {
                    const long row = rg + q;
                    float v = acc[fm][fn][q] * alpha + bv;
                    if (res) v += res[row * (long)ldres + cg];
                    if constexpr (ACT_GELU) v = gelu_exact(v);
                    if constexpr (OUTF32) {
                        if constexpr (NTC) __builtin_nontemporal_store(v, &Cf[cbase + row * ldc + cg]);
                        else               Cf[cbase + row * ldc + cg] = v;
                    } else {
                        Cs[cbase + row * ldc + cg] = f2bf(v);
                    }
                }
            }
        }
    }

    // ---- softmax stats epilogue: per-row (tile-max, tile-expsum), raw fp32 ----
    if constexpr (STATS) {
        float* sred = (float*)As;   // >= 2*BM floats
        float tmax[FM][4];
        #pragma unroll
        for (int fm = 0; fm < FM; ++fm)
            #pragma unroll
            for (int q = 0; q < 4; ++q) {
                float v = acc[fm][0][q];
                #pragma unroll
                for (int fn = 1; fn < FN; ++fn) v = fmaxf(v, acc[fm][fn][q]);
                v *= alpha;
                v = fmaxf(v, __shfl_xor(v, 1));
                v = fmaxf(v, __shfl_xor(v, 2));
                v = fmaxf(v, __shfl_xor(v, 4));
                v = fmaxf(v, __shfl_xor(v, 8));
                const int r = wr * FM * 16 + fm * 16 + (lane >> 4) * 4 + q;
                if ((lane & 15) == 0) sred[wc * BM + r] = v;
            }
        __syncthreads();
        #pragma unroll
        for (int fm = 0; fm < FM; ++fm)
            #pragma unroll
            for (int q = 0; q < 4; ++q) {
                const int r = wr * FM * 16 + fm * 16 + (lane >> 4) * 4 + q;
                tmax[fm][q] = fmaxf(sred[r], sred[BM + r]);
            }
        __syncthreads();
        #pragma unroll
        for (int fm = 0; fm < FM; ++fm)
            #pragma unroll
            for (int q = 0; q < 4; ++q) {
                float e = 0.0f;
                #pragma unroll
                for (int fn = 0; fn < FN; ++fn)
                    e += __expf(acc[fm][fn][q] * alpha - tmax[fm][q]);
                e += __shfl_xor(e, 1);
                e += __shfl_xor(e, 2);
                e += __shfl_xor(e, 4);
                e += __shfl_xor(e, 8);
                const int r = wr * FM * 16 + fm * 16 + (lane >> 4) * 4 + q;
                if ((lane & 15) == 0) sred[wc * BM + r] = e;
            }
        __syncthreads();
        if (wc == 0) {
            #pragma unroll
            for (int fm = 0; fm < FM; ++fm)
                #pragma unroll
                for (int q = 0; q < 4; ++q) {
                    const int r = wr * FM * 16 + fm * 16 + (lane >> 4) * 4 + q;
                    if ((lane & 15) == 0) {
                        float2 o; o.x = tmax[fm][q]; o.y = sred[r] + sred[BM + r];
                        st[((long)z * N_ + m0 + r) * 8 + bx] = o;
                    }
                }
        }
    }
}

// ---------------- fused QK^T-recompute + softmax(stats) + head-mix + BN -------
// Block = 16 q-rows x 64 m-cols x all 12 heads, 256 thr / 4 waves.
// S recomputed via MFMA (bitwise == pass-1 values); exp/mix in registers;
// epilogue stages tiles in LDS (reusing qs/ks) and emits BOTH the final fp32
// attn (f32x4 NT stores, 256B segments) and the bf16 mixed-P for PV.
__global__ __launch_bounds__(256)
void qksm(const short* __restrict__ qkvb, const float2* __restrict__ st,
          float* __restrict__ attn, short* __restrict__ Pbuf,
          const float* __restrict__ cw, const float* __restrict__ cb,
          const float* __restrict__ bg, const float* __restrict__ bb,
          const float* __restrict__ brm, const float* __restrict__ brv)
{
    __shared__ short qs[H_ * 16 * 64];     // 24 KB: q rows for all heads
    __shared__ short ks[2][64 * 64];       // 16 KB: per-head k tile, dbuf
    __shared__ float smx[H_][16], sinv[H_][16];
    __shared__ float coef[H_][H_], baseA[H_], scA[H_];
    const int tid = threadIdx.x, wid = tid >> 6, lane = tid & 63;

    // 1-D m204 swizzle: 8192 wgs, 1024/XCD -> XCD x owns batch x (q,k L2-hot)
    const int wg = (blockIdx.x & 7) * 1024 + (blockIdx.x >> 3);
    const int b = wg >> 10, nblk = (wg >> 4) & 63, mblk = wg & 15;
    const int n0 = nblk * 16, m0 = mblk * 64;

    if (tid < H_) {
        const float s = bg[tid] * rsqrtf(brv[tid] + 1e-5f);
        scA[tid] = s;
        baseA[tid] = (cb[tid] - brm[tid]) * s + bb[tid];
    }
    __syncthreads();
    if (tid < H_ * H_) coef[tid / H_][tid % H_] = cw[tid] * scA[tid / H_];
    if (tid < 192) {
        const int h = tid >> 4, r = tid & 15;
        const float2* sp = st + ((long)(b * H_ + h) * N_ + n0 + r) * 8;
        float2 sv[8];
        #pragma unroll
        for (int i = 0; i < 8; ++i) sv[i] = sp[i];
        float gm = sv[0].x;
        #pragma unroll
        for (int i = 1; i < 8; ++i) gm = fmaxf(gm, sv[i].x);
        float gs = 0.0f;
        #pragma unroll
        for (int i = 0; i < 8; ++i) gs += sv[i].y * __expf(sv[i].x - gm);
        smx[h][r] = gm;
        sinv[h][r] = 1.0f / gs;
    }
    __syncthreads();   // publish smx/sinv/coef; stats loads retired

    // stage q (all 12 heads x 16 rows) + k tile for head 0
    const int srow = lane >> 3, schunk = (lane & 7) ^ srow;
    const short* qbase = qkvb + (long)(b * N_ + n0) * (3 * C_);
    for (int g = wid; g < 24; g += 4) {
        const int fr = g * 8 + srow;   // fr = h*16 + n
        gload16(qbase + (long)(fr & 15) * (3 * C_) + (fr >> 4) * 64 + schunk * 8,
                &qs[g * 512]);
    }
    const short* kbase = qkvb + C_ + (long)(b * N_ + m0) * (3 * C_);
    for (int g = wid; g < 8; g += 4) {
        const int fr = g * 8 + srow;
        gload16(kbase + (long)fr * (3 * C_) + schunk * 8, &ks[0][g * 512]);
    }

    float macc[H_][4] = {};
    const int rowb = (lane >> 4) * 4;
    const int colw = wid * 16 + (lane & 15);

    for (int h = 0; h < H_; ++h) {
        asm volatile("s_waitcnt vmcnt(0)" ::: "memory");
        __builtin_amdgcn_sched_barrier(0);
        __builtin_amdgcn_s_barrier();
        // stage next head's k tile (safe: all waves past barrier => prior
        // reads of this buffer are retired); DMA overlaps this head's compute
        if (h < H_ - 1) {
            for (int g = wid; g < 8; g += 4) {
                const int fr = g * 8 + srow;
                gload16(kbase + (long)fr * (3 * C_) + (h + 1) * 64 + schunk * 8,
                        &ks[(h + 1) & 1][g * 512]);
            }
        }
        f32x4 acc = {};
        const int afr = h * 16 + (lane & 15);
        const int bfr = colw;
        #pragma unroll
        for (int kk = 0; kk < 2; ++kk) {
            const frag a  = *(const frag*)&qs[afr * 64 + (((kk * 4 + (lane >> 4)) ^ (afr & 7))) * 8];
            const frag bv = *(const frag*)&ks[h & 1][bfr * 64 + (((kk * 4 + (lane >> 4)) ^ (bfr & 7))) * 8];
            acc = __builtin_amdgcn_mfma_f32_16x16x32_bf16(a, bv, acc, 0, 0, 0);
        }
        #pragma unroll
        for (int q = 0; q < 4; ++q) {
            const float e = __expf(acc[q] * 0.125f - smx[h][rowb + q]) * sinv[h][rowb + q];
            #pragma unroll
            for (int o = 0; o < H_; ++o) macc[o][q] += coef[o][h] * e;
        }
    }

    // ---- epilogue: LDS-staged coalesced writes (6 heads per pass) ----
    __syncthreads();                       // all MFMA reads of qs/ks retired
    float* obuf = (float*)qs;              // 6 * 4 KB = 24 KB
    short* pbuf = (short*)ks;              // 6 * 2 KB = 12 KB
    const int rr = tid >> 4, cc = (tid & 15) * 4;
    #pragma unroll
    for (int ob = 0; ob < 2; ++ob) {
        #pragma unroll
        for (int hh = 0; hh < 6; ++hh) {
            const int o = ob * 6 + hh;
            #pragma unroll
            for (int q = 0; q < 4; ++q) {
                const float v = macc[o][q] + baseA[o];
                obuf[hh * 1024 + (rowb + q) * 64 + colw] = v;
                pbuf[hh * 1024 + (rowb + q) * 64 + colw] = f2bf(v);
            }
        }
        __syncthreads();
        #pragma unroll
        for (int hh = 0; hh < 6; ++hh) {
            const int o = ob * 6 + hh;
            const long pl = ((long)(b * H_ + o) << 20) + ((long)(n0 + rr) << 10) + m0 + cc;
            const f32x4 ov = *(const f32x4*)&obuf[hh * 1024 + rr * 64 + cc];
            __builtin_nontemporal_store(ov, (f32x4*)(attn + pl));
            *(s4v*)(Pbuf + pl) = *(const s4v*)&pbuf[hh * 1024 + rr * 64 + cc];
        }
        __syncthreads();
    }
}

// ---------------- v transpose: qkv bf16 [B*N,2304] -> vT [B*H][64][1024] -----
__global__ __launch_bounds__(256)
void vtrans(const short* __restrict__ qkv, short* __restrict__ vT)
{
    __shared__ short tile[64][72];
    const int bh = blockIdx.x;
    const int n0 = blockIdx.y * 64;
    const int b = bh / H_, h = bh - b * H_;
    const short* src = qkv + (long)b * N_ * (3 * C_) + 2 * C_ + h * D_;
    const int t = threadIdx.x;
    {
        const int r = t >> 2, c = (t & 3) * 16;
        const short* sp = src + (long)(n0 + r) * (3 * C_) + c;
        #pragma unroll
        for (int j = 0; j < 16; j++) tile[r][c + j] = sp[j];
    }
    __syncthreads();
    {
        const int d = t >> 2, c = (t & 3) * 16;
        short* dp = vT + (long)bh * (D_ * N_) + (long)d * N_ + n0 + c;
        #pragma unroll
        for (int j = 0; j < 16; j++) dp[j] = tile[c + j][d];
    }
}

// ---------------- launch ----------------
extern "C" void kernel_launch(void* const* d_in, const int* in_sizes, int n_in,
                              void* d_out, int out_size, void* d_ws, size_t ws_size,
                              hipStream_t stream)
{
    const float* inp    = (const float*)d_in[0];
    const float* ln1_g  = (const float*)d_in[1];
    const float* ln1_b  = (const float*)d_in[2];
    const float* qkv_w  = (const float*)d_in[3];
    const float* conv_w = (const float*)d_in[4];
    const float* conv_b = (const float*)d_in[5];
    const float* bn_g   = (const float*)d_in[6];
    const float* bn_b   = (const float*)d_in[7];
    const float* bn_rm  = (const float*)d_in[8];
    const float* bn_rv  = (const float*)d_in[9];
    const float* proj_w = (const float*)d_in[10];
    const float* proj_b = (const float*)d_in[11];
    const float* ln2_g  = (const float*)d_in[12];
    const float* ln2_b  = (const float*)d_in[13];
    const float* fc1_w  = (const float*)d_in[14];
    const float* fc1_b  = (const float*)d_in[15];
    const float* fc2_w  = (const float*)d_in[16];
    const float* fc2_b  = (const float*)d_in[17];

    float* outx = (float*)d_out;
    float* attn = outx + (long)M_ * C_;

    char* w = (char*)d_ws;
    short* wqkv  = (short*)w;  w += (long)NW0 * 2;
    short* wproj = (short*)w;  w += (long)NW1 * 2;
    short* wfc1  = (short*)w;  w += (long)NW2 * 2;
    short* wfc2  = (short*)w;  w += (long)NW3 * 2;
    short* xln   = (short*)w;  w += (long)M_ * C_ * 2;
    short* qkvb  = (short*)w;
    short* hbuf  = qkvb;       w += (long)M_ * HID_ * 2;   // max(qkv, h) region
    short* vT    = (short*)w;  w += (long)B_ * H_ * D_ * N_ * 2;
    short* Obf   = (short*)w;  w += (long)M_ * C_ * 2;
    float* xres  = (float*)w;  w += (long)M_ * C_ * 4;
    float2* st   = (float2*)w; w += (long)B_ * H_ * N_ * 8 * 8;
    short* Pbuf  = (short*)w;  w += (long)B_ * H_ * N_ * N_ * 2;   // 201 MB

    // weights -> bf16 (single fused launch; dst regions are contiguous)
    cvt_weights<<<(NW0 + NW1 + NW2 + NW3) / 1024, 256, 0, stream>>>(
        qkv_w, proj_w, fc1_w, fc2_w, wqkv);

    // 1) LN1 -> xln (bf16)
    ln_bf16<<<M_, 256, 0, stream>>>(inp, ln1_g, ln1_b, xln);

    // 2) qkv = xln @ qkv_w^T -> bf16 [8192,2304]
    gemm_mfma<128, 128, 2, 2, false, false, false, true, false, 0>
        <<<dim3(18, 64, 1), 256, 0, stream>>>(
        xln, C_, 0, 0, wqkv, C_, 0, 0, nullptr, nullptr, 0,
        qkvb, 3 * C_, 0, 0, nullptr, C_, 1.0f);

    // 3) vT = transpose(v)
    vtrans<<<dim3(B_ * H_, 16), 256, 0, stream>>>(qkvb, vT);

    // 4) pass-1: QK^T stats only (no C write) -> st
    gemm_mfma<128, 128, 2, 2, false, false, true, false, false, 0>
        <<<dim3(8, 8, 96), 256, 0, stream>>>(
        qkvb,      3 * C_, (long)N_ * 3 * C_, D_,
        qkvb + C_, 3 * C_, (long)N_ * 3 * C_, D_,
        nullptr, nullptr, 0,
        nullptr, N_, 0, 0, st, D_, 0.125f);

    // 5) pass-2: QK^T recompute + softmax + mix + BN -> fp32 attn (final) + bf16 P
    qksm<<<8192, 256, 0, stream>>>(qkvb, st, attn, Pbuf,
                                   conv_w, conv_b, bn_g, bn_b, bn_rm, bn_rv);

    // 6) O = P @ v -> bf16 [B,N,C] (bf16 gload path; z-folded 1-D swizzle)
    gemm_mfma<128, 64, 4, 1, false, false, false, true, false, 1>
        <<<dim3(768, 1, 1), 256, 0, stream>>>(
        Pbuf, N_, (long)H_ * N_ * N_, (long)N_ * N_,
        vT, N_, (long)H_ * D_ * N_, (long)D_ * N_,
        nullptr, nullptr, 0,
        Obf, C_, (long)N_ * C_, D_, nullptr, N_, 1.0f);

    // 7) x = inputs + O @ proj_w^T + proj_b -> fp32 (BN=64 grid: 768 blocks)
    gemm_mfma<128, 64, 4, 1, true, false, false, true, false, 0>
        <<<dim3(12, 64, 1), 256, 0, stream>>>(
        Obf, C_, 0, 0, wproj, C_, 0, 0, proj_b, inp, C_,
        xres, C_, 0, 0, nullptr, C_, 1.0f);

    // 8) LN2 -> xln (bf16, reuse)
    ln_bf16<<<M_, 256, 0, stream>>>(xres, ln2_g, ln2_b, xln);

    // 9) h = gelu(xln @ fc1_w^T + fc1_b) -> bf16
    gemm_mfma<128, 128, 2, 2, false, true, false, true, false, 0>
        <<<dim3(24, 64, 1), 256, 0, stream>>>(
        xln, C_, 0, 0, wfc1, C_, 0, 0, fc1_b, nullptr, 0,
        hbuf, HID_, 0, 0, nullptr, C_, 1.0f);

    // 10) out = x + h @ fc2_w^T + fc2_b -> fp32 NT (BN=64 grid: 768 blocks)
    gemm_mfma<128, 64, 4, 1, true, false, false, true, true, 0>
        <<<dim3(12, 64, 1), 256, 0, stream>>>(
        hbuf, HID_, 0, 0, wfc2, HID_, 0, 0, fc2_b, xres, C_,
        outx, C_, 0, 0, nullptr, HID_, 1.0f);
}